// Round 1
// baseline (368.882 us; speedup 1.0000x reference)
//
#include <hip/hip_runtime.h>
#include <cstddef>

#define G_    128
#define NPG_  256
#define EPG_  4096
#define NN_   32768
#define EE_   524288
#define KK_   2048
#define GK_   262144

// d_out layout (floats): [score E][causal_w GK][conf_w GK][causal_ei 2*GK][conf_ei 2*GK][cmask N][dmask N]
#define O_CW  524288
#define O_DW  786432
#define O_CEI 1048576
#define O_FEI 1572864
#define O_CM  2097152
#define O_DM  2129920

typedef float v4f __attribute__((ext_vector_type(4)));
typedef unsigned long long u64;

struct BiasCfg {
  const float* b[8];
};

__device__ __forceinline__ void cswap(u64& a, u64& b, bool d) {
  u64 hi = a > b ? a : b, lo = a > b ? b : a;
  a = d ? hi : lo;
  b = d ? lo : hi;
}

// ---------------- GEMM body, W from pre-transposed global; nt-envelope rule (r6/7/8/9/13):
// <=1 outstanding nt panel stream per block — enforce with __syncthreads() AFTER each cb's
// store burst. Removing that barrier (r13) caused ~20x HBM write amplification. ----------------
__device__ __forceinline__ void gemm_wt_body(const float* __restrict__ in, int istride,
                                             const float* __restrict__ WT, int wstride,
                                             const BiasCfg& bc, int ncb,
                                             float* __restrict__ out, int ostride,
                                             int bx, float* xT) {
  const int tid = threadIdx.x;
  const int r0 = bx * 64;
#pragma unroll
  for (int it = 0; it < 16; ++it) {
    int idx = tid + it * 256;
    int rr = idx >> 6, kk = idx & 63;
    xT[kk * 68 + rr] = in[(r0 + rr) * istride + kk];
  }
  __syncthreads();
  const int c4 = (tid & 15) * 4;
  const int r4 = (tid >> 4) * 4;
  for (int cb = 0; cb < ncb; ++cb) {
    const float* wp = WT + cb * 64 + c4;
    const float* bp = bc.b[cb];
    float acc[4][4] = {};
#pragma unroll
    for (int k = 0; k < 64; ++k) {
      float4 xv = *(const float4*)&xT[k * 68 + r4];
      float4 wv = *(const float4*)&wp[(size_t)k * wstride];
      float xr[4] = {xv.x, xv.y, xv.z, xv.w};
      float wc[4] = {wv.x, wv.y, wv.z, wv.w};
#pragma unroll
      for (int a = 0; a < 4; ++a)
#pragma unroll
        for (int b = 0; b < 4; ++b)
          acc[a][b] = fmaf(xr[a], wc[b], acc[a][b]);
    }
    float bx4[4] = {0.f, 0.f, 0.f, 0.f};
    if (bp) {
      float4 bb = *(const float4*)&bp[c4];
      bx4[0] = bb.x; bx4[1] = bb.y; bx4[2] = bb.z; bx4[3] = bb.w;
    }
#pragma unroll
    for (int ri = 0; ri < 4; ++ri) {
      v4f st;
      st.x = acc[ri][0] + bx4[0];
      st.y = acc[ri][1] + bx4[1];
      st.z = acc[ri][2] + bx4[2];
      st.w = acc[ri][3] + bx4[3];
      __builtin_nontemporal_store(st, (v4f*)&out[(r0 + r4 + ri) * ostride + cb * 64 + c4]);
    }
    __syncthreads();  // drain nt burst (vmcnt(0)) — the nt-envelope invariant
  }
}

__global__ __launch_bounds__(256, 4) void gemm_wt(const float* __restrict__ in, int istride,
                                                  const float* __restrict__ WT, int wstride,
                                                  BiasCfg bc, int ncb,
                                                  float* __restrict__ out, int ostride) {
  __shared__ float xT[64 * 68];
  gemm_wt_body(in, istride, WT, wstride, bc, ncb, out, ostride, blockIdx.x, xT);
}

// ---------------- prep: weight transposes (WmT/W1T/W2T) + zero masks ----------------
__global__ __launch_bounds__(256) void prep_kernel(const float* __restrict__ Wm1,
                                                   const float* __restrict__ W11, const float* __restrict__ W12,
                                                   const float* __restrict__ W13,
                                                   const float* __restrict__ W21, const float* __restrict__ W22,
                                                   const float* __restrict__ W23,
                                                   float* __restrict__ WmT, float* __restrict__ W1T,
                                                   float* __restrict__ W2T, int* __restrict__ masks) {
  const int b = blockIdx.x;
  const int tid = threadIdx.x;
  if (b < 64) {
    const int k = b;
#pragma unroll
    for (int t = 0; t < 2; ++t) {
      int j = t * 256 + tid;
      int row = j & 255;
      int koff = (j < 256) ? 0 : 64;
      WmT[k * 512 + j] = Wm1[row * 128 + koff + k];
    }
  } else if (b < 80) {
    const int kb = (b - 64) * 4;
    if (tid < 192) {
      int cb = tid >> 6, c = tid & 63;
      const float* Wsrc = (cb == 0) ? W11 : (cb == 1) ? W12 : W13;
#pragma unroll
      for (int s = 0; s < 4; ++s) {
        int k = kb + s;
        W1T[k * 192 + tid] = Wsrc[c * 64 + k];
      }
    }
  } else if (b < 96) {
    const int kb = (b - 80) * 4;
    if (tid < 192) {
      int cb = tid >> 6, c = tid & 63;
      const float* Wsrc = (cb == 0) ? W21 : (cb == 1) ? W22 : W23;
#pragma unroll
      for (int s = 0; s < 4; ++s) {
        int k = kb + s;
        W2T[k * 192 + tid] = Wsrc[c * 64 + k];
      }
    }
  } else {
    int idx = (b - 96) * 1024 + tid * 4;  // 64 blocks x 1024 ints = 65536 = 2*NN
    int4 z = {0, 0, 0, 0};
    *(int4*)&masks[idx] = z;
  }
}

// ---------------- build_dense: per-(group, col-half) LDS accumulation — no global atomics,
// no MT memset (every cell written), Wc = LDS column sums (no contention) ----------------
__global__ __launch_bounds__(256) void build_dense(const int* __restrict__ ei, const float* __restrict__ ea,
                                                   float* __restrict__ MT, float* __restrict__ Wc) {
  __shared__ float acc[NPG_ * 128];  // 128 KB: 256 rows x 128 cols (this block's column half)
  const int tid = threadIdx.x;
  const int g = blockIdx.x >> 1;
  const int c0 = (blockIdx.x & 1) * 128;
  const int gbase = g * NPG_;
  const size_t mbase = (size_t)g << 16;
  for (int i = tid * 4; i < NPG_ * 128; i += 1024) {
    float4 z = {0.f, 0.f, 0.f, 0.f};
    *(float4*)&acc[i] = z;
  }
  __syncthreads();
  const int ebase = g * EPG_;
#pragma unroll
  for (int it = 0; it < 16; ++it) {
    int e = ebase + it * 256 + tid;
    int r = ei[e] - gbase;
    int ch = ei[EE_ + e] - gbase - c0;
    float w = ea[e];
    if ((unsigned)ch < 128u) atomicAdd(&acc[r * 128 + ch], w);
  }
  __syncthreads();
  // write the half-slab: each row contributes 512 B aligned chunk
  for (int i = tid; i < NPG_ * 32; i += 256) {
    int r = i >> 5, c4 = (i & 31) * 4;
    *(float4*)&MT[mbase + (size_t)r * 256 + c0 + c4] = *(const float4*)&acc[r * 128 + c4];
  }
  // Wc column sums (lanes own columns; per-lane serial over r)
  if (tid < 128) {
    float s = 0.f;
    for (int r = 0; r < NPG_; ++r) s += acc[r * 128 + tid];
    Wc[gbase + c0 + tid] = s;
  }
}

// ---------------- dense leconv aggregation: h[c] = sum_r MT[r][c]*A[r] - Wc[c]*B[c] + C[c]
// (v2: float4 staging — 4x fewer global-load and LDS-write instructions) ----------------
__global__ __launch_bounds__(256) void mm_agg(const float* __restrict__ MT, const float* __restrict__ buf,
                                              const float* __restrict__ Wc, float* __restrict__ hout,
                                              int do_relu) {
  __shared__ float Ms[64 * 72];
  __shared__ float As[64 * 72];
  const int tid = threadIdx.x;
  const int g = blockIdx.x >> 2;
  const int c0 = (blockIdx.x & 3) * 64;
  const int gbase = g * NPG_;
  const size_t mbase = (size_t)g << 16;
  const int c4 = (tid >> 4) * 4;   // output node within tile
  const int k4 = (tid & 15) * 4;   // feature (lane-contiguous)
  float acc[4][4] = {};
  for (int kc = 0; kc < 4; ++kc) {
#pragma unroll
    for (int it = 0; it < 4; ++it) {
      int idx = tid + it * 256;       // 0..1023
      int rr = idx >> 4, c16 = (idx & 15) * 4;
      *(float4*)&Ms[rr * 72 + c16] = *(const float4*)&MT[mbase + (size_t)(kc * 64 + rr) * 256 + c0 + c16];
      *(float4*)&As[rr * 72 + c16] = *(const float4*)&buf[(gbase + kc * 64 + rr) * 192 + c16];
    }
    __syncthreads();
#pragma unroll
    for (int r = 0; r < 64; ++r) {
      float4 mv = *(const float4*)&Ms[r * 72 + c4];
      float4 av = *(const float4*)&As[r * 72 + k4];
      float mr[4] = {mv.x, mv.y, mv.z, mv.w};
      float ak[4] = {av.x, av.y, av.z, av.w};
#pragma unroll
      for (int ci = 0; ci < 4; ++ci)
#pragma unroll
        for (int ki = 0; ki < 4; ++ki)
          acc[ci][ki] = fmaf(mr[ci], ak[ki], acc[ci][ki]);
    }
    __syncthreads();
  }
#pragma unroll
  for (int ci = 0; ci < 4; ++ci) {
    int n = gbase + c0 + c4 + ci;
    float wcn = Wc[n];
    float4 b4 = *(const float4*)&buf[n * 192 + 64 + k4];
    float4 cc4 = *(const float4*)&buf[n * 192 + 128 + k4];
    float4 st;
    st.x = acc[ci][0] - wcn * b4.x + cc4.x;
    st.y = acc[ci][1] - wcn * b4.y + cc4.y;
    st.z = acc[ci][2] - wcn * b4.z + cc4.z;
    st.w = acc[ci][3] - wcn * b4.w + cc4.w;
    if (do_relu) {
      st.x = fmaxf(st.x, 0.f); st.y = fmaxf(st.y, 0.f);
      st.z = fmaxf(st.z, 0.f); st.w = fmaxf(st.w, 0.f);
    }
    *(float4*)&hout[n * 64 + k4] = st;
  }
}

// ---------------- fused edge scores v6: direct-from-L2 gather, no LDS staging.
// v5 was LDS-pipe-bound: ~62% of its 54us was ds_read_b128 + 1.2e7 conflict cycles
// (stride-20 rows -> start banks limited to 8 classes; no aligned stride can beat that).
// v6: 16 lanes per edge, lane s owns float4s {s, s+16, s+32, s+48} of the 1KB P row
// (same for Q row at +256 floats) -> each wave instr reads 4 contiguous 256B segments,
// every 64B L2 line fetched exactly once. Group slab (512KB) is L2-resident via the
// same-XCD swizzle (blocks with equal blockIdx&127 are congruent mod 8).
// 2-deep edge pipeline (A/B reg sets, ~16 loads in flight/lane) hides L2 latency.
// Scores reduced via 4x shfl_xor, buffered in LDS, written coalesced as float2. ----------------
struct EdgeRegs { float4 p0, p1, p2, p3, q0, q1, q2, q3; };

__device__ __forceinline__ void load_edge(const float* __restrict__ pq, int r, int c, int s, EdgeRegs& R) {
  const float4* Pp = (const float4*)(pq + (size_t)r * 512) + s;
  const float4* Qp = (const float4*)(pq + (size_t)c * 512 + 256) + s;
  R.p0 = Pp[0];  R.p1 = Pp[16]; R.p2 = Pp[32]; R.p3 = Pp[48];
  R.q0 = Qp[0];  R.q1 = Qp[16]; R.q2 = Qp[32]; R.q3 = Qp[48];
}

#define ACC4(A, W, P, Q)                                  \
  A = fmaf(W.x, fmaxf(P.x + Q.x, 0.f), A);                \
  A = fmaf(W.y, fmaxf(P.y + Q.y, 0.f), A);                \
  A = fmaf(W.z, fmaxf(P.z + Q.z, 0.f), A);                \
  A = fmaf(W.w, fmaxf(P.w + Q.w, 0.f), A);

__device__ __forceinline__ float edge_score(const EdgeRegs& R, float4 w0, float4 w1, float4 w2, float4 w3) {
  float a0 = 0.f, a1 = 0.f;  // 2 accumulators: halve the serial fma chain
  ACC4(a0, w0, R.p0, R.q0);
  ACC4(a1, w1, R.p1, R.q1);
  ACC4(a0, w2, R.p2, R.q2);
  ACC4(a1, w3, R.p3, R.q3);
  return a0 + a1;
}

__global__ __launch_bounds__(256, 4) void score_v6(const float* __restrict__ pq, const int* __restrict__ ei,
                                                   const float* __restrict__ wm2, const float* __restrict__ bm2,
                                                   float* __restrict__ out) {
  __shared__ float sbuf[512];
  const int tid = threadIdx.x;
  const int g = blockIdx.x & 127;       // same-g blocks all ≡ g (mod 8) -> same XCD, pq L2 reuse
  const int eighth = blockIdx.x >> 7;
  const int ebase = g * EPG_ + eighth * 512;
  const int slot = tid >> 4;            // 16 edge-slots per block
  const int s = tid & 15;               // lane-within-edge: owns feats {4s+64i}
  const float4 w0 = *(const float4*)&wm2[s * 4];
  const float4 w1 = *(const float4*)&wm2[64 + s * 4];
  const float4 w2 = *(const float4*)&wm2[128 + s * 4];
  const float4 w3 = *(const float4*)&wm2[192 + s * 4];
  const float beta = bm2[0];
  const int e0 = ebase + slot * 32;

  EdgeRegs A, B;
  {
    int r = ei[e0], c = ei[EE_ + e0];
    load_edge(pq, r, c, s, A);
  }
#pragma unroll 1
  for (int n = 0; n < 32; n += 2) {
    {  // prefetch edge n+1 into B while A's loads drain / compute proceeds
      int e1 = e0 + n + 1;
      int r = ei[e1], c = ei[EE_ + e1];
      load_edge(pq, r, c, s, B);
    }
    float a = edge_score(A, w0, w1, w2, w3);
    a += __shfl_xor(a, 1); a += __shfl_xor(a, 2);
    a += __shfl_xor(a, 4); a += __shfl_xor(a, 8);
    if (s == 0) sbuf[slot * 32 + n] = a;
    if (n + 2 < 32) {  // prefetch edge n+2 into A before computing B
      int e2 = e0 + n + 2;
      int r = ei[e2], c = ei[EE_ + e2];
      load_edge(pq, r, c, s, A);
    }
    float b = edge_score(B, w0, w1, w2, w3);
    b += __shfl_xor(b, 1); b += __shfl_xor(b, 2);
    b += __shfl_xor(b, 4); b += __shfl_xor(b, 8);
    if (s == 0) sbuf[slot * 32 + n + 1] = b;
  }
  __syncthreads();
  float2 v = *(const float2*)&sbuf[tid * 2];
  v.x += beta; v.y += beta;
  *(float2*)&out[ebase + tid * 2] = v;
}

// ---------------- bitonic argsort v4 (proven): registers + shfl_xor; LDS only for j>=256 ----------------
__global__ __launch_bounds__(1024) void sort_kernel(float* __restrict__ out, const int* __restrict__ ei,
                                                    int* __restrict__ kg, int* __restrict__ dg,
                                                    int* __restrict__ cmask, int* __restrict__ dmask) {
  __shared__ u64 keys[EPG_];
  const int g = blockIdx.x;
  const int tid = threadIdx.x;
  const int b = 4 * tid;
  u64 e[4];
  {
    float4 s4 = *(const float4*)&out[g * EPG_ + b];
    float sv[4] = {s4.x, s4.y, s4.z, s4.w};
#pragma unroll
    for (int s = 0; s < 4; ++s) {
      unsigned u = __float_as_uint(sv[s]);
      u = (u & 0x80000000u) ? ~u : (u | 0x80000000u);
      e[s] = ((u64)u << 32) | (unsigned)(~(b + s));
    }
  }
  cswap(e[0], e[1], true);
  cswap(e[2], e[3], false);
  {
    bool d = ((b & 4) == 0);
    cswap(e[0], e[2], d); cswap(e[1], e[3], d);
    cswap(e[0], e[1], d); cswap(e[2], e[3], d);
  }
  for (int k = 8; k <= EPG_; k <<= 1) {
    if (k >= 512) {
#pragma unroll
      for (int s = 0; s < 4; ++s) keys[b + s] = e[s];
      __syncthreads();
      for (int j = k >> 1; j >= 256; j >>= 1) {
        const int jm1 = j - 1;
        const int p0 = tid, p1 = tid + 1024;
        const int i0 = ((p0 & ~jm1) << 1) | (p0 & jm1);
        const int i1 = ((p1 & ~jm1) << 1) | (p1 & jm1);
        u64 a0 = keys[i0], b0 = keys[i0 + j];
        u64 a1 = keys[i1], b1 = keys[i1 + j];
        bool d0 = ((i0 & k) == 0), d1 = ((i1 & k) == 0);
        u64 hi0 = a0 > b0 ? a0 : b0, lo0 = a0 > b0 ? b0 : a0;
        u64 hi1 = a1 > b1 ? a1 : b1, lo1 = a1 > b1 ? b1 : a1;
        keys[i0]     = d0 ? hi0 : lo0;
        keys[i0 + j] = d0 ? lo0 : hi0;
        keys[i1]     = d1 ? hi1 : lo1;
        keys[i1 + j] = d1 ? lo1 : hi1;
        __syncthreads();
      }
#pragma unroll
      for (int s = 0; s < 4; ++s) e[s] = keys[b + s];
    }
    const bool d = ((tid & (k >> 2)) == 0);
    for (int j = (k >> 1) > 128 ? 128 : (k >> 1); j >= 4; j >>= 1) {
      const int delta = j >> 2;
      const bool lower = ((tid & delta) == 0);
      const bool keepmax = (lower == d);
#pragma unroll
      for (int s = 0; s < 4; ++s) {
        u64 p = __shfl_xor(e[s], delta);
        u64 mx = e[s] > p ? e[s] : p;
        u64 mn = e[s] > p ? p : e[s];
        e[s] = keepmax ? mx : mn;
      }
    }
    cswap(e[0], e[2], d); cswap(e[1], e[3], d);
    cswap(e[0], e[1], d); cswap(e[2], e[3], d);
  }
#pragma unroll
  for (int s = 0; s < 4; ++s) {
    const int p = b + s;
    u64 kv = e[s];
    int i = (int)(~(unsigned)kv);
    unsigned hi = (unsigned)(kv >> 32);
    unsigned ub = (hi & 0x80000000u) ? (hi ^ 0x80000000u) : ~hi;
    float sc = __uint_as_float(ub);
    int ed = g * EPG_ + i;
    int r = ei[ed], c = ei[EE_ + ed];
    if (p < KK_) {
      out[O_CW + g * KK_ + p] = sc;
      kg[g * KK_ + p] = ed;
      cmask[r] = 1; cmask[c] = 1;
    } else {
      int q = p - KK_;
      out[O_DW + g * KK_ + q] = -sc;
      dg[g * KK_ + q] = ed;
      dmask[r] = 1; dmask[c] = 1;
    }
  }
}

// ---------------- inclusive scan of masks -> nid (cumsum-1); 1 block per mask ----------------
__global__ __launch_bounds__(1024) void scan_kernel(const int* __restrict__ masks, int* __restrict__ nids) {
  const int which = blockIdx.x;
  const int* m = masks + which * NN_;
  int* nid = nids + which * NN_;
  const int tid = threadIdx.x;
  const int base = tid * 32;
  int local[32];
  int sum = 0;
#pragma unroll
  for (int j = 0; j < 32; ++j) { local[j] = m[base + j]; sum += local[j]; }
  __shared__ int ps[1024];
  ps[tid] = sum;
  __syncthreads();
  for (int off = 1; off < 1024; off <<= 1) {
    int v = (tid >= off) ? ps[tid - off] : 0;
    __syncthreads();
    ps[tid] += v;
    __syncthreads();
  }
  int run = ps[tid] - sum;
#pragma unroll
  for (int j = 0; j < 32; ++j) { run += local[j]; nid[base + j] = run - 1; }
}

// ---------------- final gathers ----------------
__global__ __launch_bounds__(256) void finalize_kernel(const int* __restrict__ kg, const int* __restrict__ dg,
                                                       const int* __restrict__ ei,
                                                       const int* __restrict__ nid_c, const int* __restrict__ nid_d,
                                                       const int* __restrict__ cmask, const int* __restrict__ dmask,
                                                       float* __restrict__ out) {
  const int p = blockIdx.x * 256 + threadIdx.x;
  int e = kg[p];
  out[O_CEI + p]       = (float)nid_c[ei[e]];
  out[O_CEI + GK_ + p] = (float)nid_c[ei[EE_ + e]];
  int e2 = dg[p];
  out[O_FEI + p]       = (float)nid_d[ei[e2]];
  out[O_FEI + GK_ + p] = (float)nid_d[ei[EE_ + e2]];
  if (p < NN_) {
    out[O_CM + p] = (float)cmask[p];
    out[O_DM + p] = (float)dmask[p];
  }
}

extern "C" void kernel_launch(void* const* d_in, const int* in_sizes, int n_in,
                              void* d_out, int out_size, void* d_ws, size_t ws_size,
                              hipStream_t stream) {
  (void)in_sizes; (void)n_in; (void)out_size; (void)ws_size;
  const float* x   = (const float*)d_in[0];
  const float* ea  = (const float*)d_in[1];
  const float* W11 = (const float*)d_in[2];
  const float* b11 = (const float*)d_in[3];
  const float* W12 = (const float*)d_in[4];
  const float* W13 = (const float*)d_in[5];
  const float* b13 = (const float*)d_in[6];
  const float* W21 = (const float*)d_in[7];
  const float* b21 = (const float*)d_in[8];
  const float* W22 = (const float*)d_in[9];
  const float* W23 = (const float*)d_in[10];
  const float* b23 = (const float*)d_in[11];
  const float* Wm1 = (const float*)d_in[12];
  const float* bm1 = (const float*)d_in[13];
  const float* Wm2 = (const float*)d_in[14];
  const float* bm2 = (const float*)d_in[15];
  const int*   ei  = (const int*)d_in[16];
  float* out = (float*)d_out;
  float* ws  = (float*)d_ws;

  // workspace (float offsets), phase-overlapped (unchanged 78.1 MB footprint):
  //   MT  [0, 8388608)          32 MB   (dead after mm_agg #2; fully written by build_dense — no memset)
  //   Wc  [8388608, 8421376)    128 KB  (fully written by build_dense)
  //   buf [8421376, 14712832)   24 MB   (dead after mm_agg #2)
  //   pq  [0, 16777216)         64 MB   overlaps MT/Wc/buf, written after all dead
  //   h_c [16777216, 18874368)  8 MB
  //   ints from 18874368: kg GK, dg GK, cmask N, dmask N, nid_c N, nid_d N
  //   WT aliases kg: WmT 32768 + W1T 12288 + W2T 12288 = 57344 floats < GK.
  float* MT  = ws;
  float* Wc  = ws + 8388608;
  float* buf = ws + 8421376;
  float* pq  = ws;
  float* h_c = ws + 16777216;
  int* kg    = (int*)(ws + 18874368);
  int* dg    = kg + GK_;
  int* cmask = dg + GK_;
  int* dmask = cmask + NN_;
  int* nid_c = dmask + NN_;
  int* nid_d = nid_c + NN_;
  float* WmT = ws + 18874368;            // aliases kg
  float* W1T = WmT + 32768;
  float* W2T = W1T + 12288;

  prep_kernel<<<160, 256, 0, stream>>>(Wm1, W11, W12, W13, W21, W22, W23, WmT, W1T, W2T, cmask);

  build_dense<<<256, 256, 0, stream>>>(ei, ea, MT, Wc);

  BiasCfg bc1{};
  bc1.b[0] = b11; bc1.b[1] = nullptr; bc1.b[2] = b13;
  gemm_wt<<<512, 256, 0, stream>>>(x, 64, W1T, 192, bc1, 3, buf, 192);

  mm_agg<<<512, 256, 0, stream>>>(MT, buf, Wc, h_c, /*relu=*/1);

  BiasCfg bc2{};
  bc2.b[0] = b21; bc2.b[1] = nullptr; bc2.b[2] = b23;
  gemm_wt<<<512, 256, 0, stream>>>(h_c, 64, W2T, 192, bc2, 3, buf, 192);

  mm_agg<<<512, 256, 0, stream>>>(MT, buf, Wc, h_c, /*relu=*/0);

  BiasCfg bc3{};
  for (int cb = 0; cb < 4; ++cb) { bc3.b[cb] = bm1 + cb * 64; bc3.b[cb + 4] = nullptr; }
  gemm_wt<<<512, 256, 0, stream>>>(h_c, 64, WmT, 512, bc3, 8, pq, 512);

  score_v6<<<1024, 256, 0, stream>>>(pq, ei, Wm2, bm2, out);

  sort_kernel<<<G_, 1024, 0, stream>>>(out, ei, kg, dg, cmask, dmask);

  scan_kernel<<<2, 1024, 0, stream>>>(cmask, nid_c);

  finalize_kernel<<<GK_ / 256, 256, 0, stream>>>(kg, dg, ei, nid_c, nid_d, cmask, dmask, out);
}

// Round 2
// 347.606 us; speedup vs baseline: 1.0612x; 1.0612x over previous
//
#include <hip/hip_runtime.h>
#include <cstddef>

#define G_    128
#define NPG_  256
#define EPG_  4096
#define NN_   32768
#define EE_   524288
#define KK_   2048
#define GK_   262144

// d_out layout (floats): [score E][causal_w GK][conf_w GK][causal_ei 2*GK][conf_ei 2*GK][cmask N][dmask N]
#define O_CW  524288
#define O_DW  786432
#define O_CEI 1048576
#define O_FEI 1572864
#define O_CM  2097152
#define O_DM  2129920

typedef float v4f __attribute__((ext_vector_type(4)));
typedef unsigned long long u64;

struct BiasCfg {
  const float* b[8];
};

__device__ __forceinline__ void cswap(u64& a, u64& b, bool d) {
  u64 hi = a > b ? a : b, lo = a > b ? b : a;
  a = d ? hi : lo;
  b = d ? lo : hi;
}

// ---------------- GEMM body, W from pre-transposed global; nt-envelope rule (r6/7/8/9/13):
// <=1 outstanding nt panel stream per block — enforce with __syncthreads() AFTER each cb's
// store burst. Removing that barrier (r13) caused ~20x HBM write amplification. ----------------
__device__ __forceinline__ void gemm_wt_body(const float* __restrict__ in, int istride,
                                             const float* __restrict__ WT, int wstride,
                                             const BiasCfg& bc, int ncb,
                                             float* __restrict__ out, int ostride,
                                             int bx, float* xT) {
  const int tid = threadIdx.x;
  const int r0 = bx * 64;
#pragma unroll
  for (int it = 0; it < 16; ++it) {
    int idx = tid + it * 256;
    int rr = idx >> 6, kk = idx & 63;
    xT[kk * 68 + rr] = in[(r0 + rr) * istride + kk];
  }
  __syncthreads();
  const int c4 = (tid & 15) * 4;
  const int r4 = (tid >> 4) * 4;
  for (int cb = 0; cb < ncb; ++cb) {
    const float* wp = WT + cb * 64 + c4;
    const float* bp = bc.b[cb];
    float acc[4][4] = {};
#pragma unroll
    for (int k = 0; k < 64; ++k) {
      float4 xv = *(const float4*)&xT[k * 68 + r4];
      float4 wv = *(const float4*)&wp[(size_t)k * wstride];
      float xr[4] = {xv.x, xv.y, xv.z, xv.w};
      float wc[4] = {wv.x, wv.y, wv.z, wv.w};
#pragma unroll
      for (int a = 0; a < 4; ++a)
#pragma unroll
        for (int b = 0; b < 4; ++b)
          acc[a][b] = fmaf(xr[a], wc[b], acc[a][b]);
    }
    float bx4[4] = {0.f, 0.f, 0.f, 0.f};
    if (bp) {
      float4 bb = *(const float4*)&bp[c4];
      bx4[0] = bb.x; bx4[1] = bb.y; bx4[2] = bb.z; bx4[3] = bb.w;
    }
#pragma unroll
    for (int ri = 0; ri < 4; ++ri) {
      v4f st;
      st.x = acc[ri][0] + bx4[0];
      st.y = acc[ri][1] + bx4[1];
      st.z = acc[ri][2] + bx4[2];
      st.w = acc[ri][3] + bx4[3];
      __builtin_nontemporal_store(st, (v4f*)&out[(r0 + r4 + ri) * ostride + cb * 64 + c4]);
    }
    __syncthreads();  // drain nt burst (vmcnt(0)) — the nt-envelope invariant
  }
}

__global__ __launch_bounds__(256, 4) void gemm_wt(const float* __restrict__ in, int istride,
                                                  const float* __restrict__ WT, int wstride,
                                                  BiasCfg bc, int ncb,
                                                  float* __restrict__ out, int ostride) {
  __shared__ float xT[64 * 68];
  gemm_wt_body(in, istride, WT, wstride, bc, ncb, out, ostride, blockIdx.x, xT);
}

// ---------------- prep: weight transposes (WmT/W1T/W2T) + zero masks ----------------
__global__ __launch_bounds__(256) void prep_kernel(const float* __restrict__ Wm1,
                                                   const float* __restrict__ W11, const float* __restrict__ W12,
                                                   const float* __restrict__ W13,
                                                   const float* __restrict__ W21, const float* __restrict__ W22,
                                                   const float* __restrict__ W23,
                                                   float* __restrict__ WmT, float* __restrict__ W1T,
                                                   float* __restrict__ W2T, int* __restrict__ masks) {
  const int b = blockIdx.x;
  const int tid = threadIdx.x;
  if (b < 64) {
    const int k = b;
#pragma unroll
    for (int t = 0; t < 2; ++t) {
      int j = t * 256 + tid;
      int row = j & 255;
      int koff = (j < 256) ? 0 : 64;
      WmT[k * 512 + j] = Wm1[row * 128 + koff + k];
    }
  } else if (b < 80) {
    const int kb = (b - 64) * 4;
    if (tid < 192) {
      int cb = tid >> 6, c = tid & 63;
      const float* Wsrc = (cb == 0) ? W11 : (cb == 1) ? W12 : W13;
#pragma unroll
      for (int s = 0; s < 4; ++s) {
        int k = kb + s;
        W1T[k * 192 + tid] = Wsrc[c * 64 + k];
      }
    }
  } else if (b < 96) {
    const int kb = (b - 80) * 4;
    if (tid < 192) {
      int cb = tid >> 6, c = tid & 63;
      const float* Wsrc = (cb == 0) ? W21 : (cb == 1) ? W22 : W23;
#pragma unroll
      for (int s = 0; s < 4; ++s) {
        int k = kb + s;
        W2T[k * 192 + tid] = Wsrc[c * 64 + k];
      }
    }
  } else {
    int idx = (b - 96) * 1024 + tid * 4;  // 64 blocks x 1024 ints = 65536 = 2*NN
    int4 z = {0, 0, 0, 0};
    *(int4*)&masks[idx] = z;
  }
}

// ---------------- build_dense: per-(group, col-half) LDS accumulation — no global atomics,
// no MT memset (every cell written), Wc = LDS column sums (no contention) ----------------
__global__ __launch_bounds__(256) void build_dense(const int* __restrict__ ei, const float* __restrict__ ea,
                                                   float* __restrict__ MT, float* __restrict__ Wc) {
  __shared__ float acc[NPG_ * 128];  // 128 KB: 256 rows x 128 cols (this block's column half)
  const int tid = threadIdx.x;
  const int g = blockIdx.x >> 1;
  const int c0 = (blockIdx.x & 1) * 128;
  const int gbase = g * NPG_;
  const size_t mbase = (size_t)g << 16;
  for (int i = tid * 4; i < NPG_ * 128; i += 1024) {
    float4 z = {0.f, 0.f, 0.f, 0.f};
    *(float4*)&acc[i] = z;
  }
  __syncthreads();
  const int ebase = g * EPG_;
#pragma unroll
  for (int it = 0; it < 16; ++it) {
    int e = ebase + it * 256 + tid;
    int r = ei[e] - gbase;
    int ch = ei[EE_ + e] - gbase - c0;
    float w = ea[e];
    if ((unsigned)ch < 128u) atomicAdd(&acc[r * 128 + ch], w);
  }
  __syncthreads();
  // write the half-slab: each row contributes 512 B aligned chunk
  for (int i = tid; i < NPG_ * 32; i += 256) {
    int r = i >> 5, c4 = (i & 31) * 4;
    *(float4*)&MT[mbase + (size_t)r * 256 + c0 + c4] = *(const float4*)&acc[r * 128 + c4];
  }
  // Wc column sums (lanes own columns; per-lane serial over r)
  if (tid < 128) {
    float s = 0.f;
    for (int r = 0; r < NPG_; ++r) s += acc[r * 128 + tid];
    Wc[gbase + c0 + tid] = s;
  }
}

// ---------------- dense leconv aggregation: h[c] = sum_r MT[r][c]*A[r] - Wc[c]*B[c] + C[c]
// (v2: float4 staging — 4x fewer global-load and LDS-write instructions) ----------------
__global__ __launch_bounds__(256) void mm_agg(const float* __restrict__ MT, const float* __restrict__ buf,
                                              const float* __restrict__ Wc, float* __restrict__ hout,
                                              int do_relu) {
  __shared__ float Ms[64 * 72];
  __shared__ float As[64 * 72];
  const int tid = threadIdx.x;
  const int g = blockIdx.x >> 2;
  const int c0 = (blockIdx.x & 3) * 64;
  const int gbase = g * NPG_;
  const size_t mbase = (size_t)g << 16;
  const int c4 = (tid >> 4) * 4;   // output node within tile
  const int k4 = (tid & 15) * 4;   // feature (lane-contiguous)
  float acc[4][4] = {};
  for (int kc = 0; kc < 4; ++kc) {
#pragma unroll
    for (int it = 0; it < 4; ++it) {
      int idx = tid + it * 256;       // 0..1023
      int rr = idx >> 4, c16 = (idx & 15) * 4;
      *(float4*)&Ms[rr * 72 + c16] = *(const float4*)&MT[mbase + (size_t)(kc * 64 + rr) * 256 + c0 + c16];
      *(float4*)&As[rr * 72 + c16] = *(const float4*)&buf[(gbase + kc * 64 + rr) * 192 + c16];
    }
    __syncthreads();
#pragma unroll
    for (int r = 0; r < 64; ++r) {
      float4 mv = *(const float4*)&Ms[r * 72 + c4];
      float4 av = *(const float4*)&As[r * 72 + k4];
      float mr[4] = {mv.x, mv.y, mv.z, mv.w};
      float ak[4] = {av.x, av.y, av.z, av.w};
#pragma unroll
      for (int ci = 0; ci < 4; ++ci)
#pragma unroll
        for (int ki = 0; ki < 4; ++ki)
          acc[ci][ki] = fmaf(mr[ci], ak[ki], acc[ci][ki]);
    }
    __syncthreads();
  }
#pragma unroll
  for (int ci = 0; ci < 4; ++ci) {
    int n = gbase + c0 + c4 + ci;
    float wcn = Wc[n];
    float4 b4 = *(const float4*)&buf[n * 192 + 64 + k4];
    float4 cc4 = *(const float4*)&buf[n * 192 + 128 + k4];
    float4 st;
    st.x = acc[ci][0] - wcn * b4.x + cc4.x;
    st.y = acc[ci][1] - wcn * b4.y + cc4.y;
    st.z = acc[ci][2] - wcn * b4.z + cc4.z;
    st.w = acc[ci][3] - wcn * b4.w + cc4.w;
    if (do_relu) {
      st.x = fmaxf(st.x, 0.f); st.y = fmaxf(st.y, 0.f);
      st.z = fmaxf(st.z, 0.f); st.w = fmaxf(st.w, 0.f);
    }
    *(float4*)&hout[n * 64 + k4] = st;
  }
}

// ---------------- fused edge scores v7: LDS staging (v5 structure) with FEATURE-MAJOR layout.
// History: v5 (node-major stride-20, float4 gather) = 54us, 1.2e7 bank-conflict cycles — any
// 16B-aligned row stride limits ds_read_b128 start banks to the 8 multiples-of-4 classes, and
// random rows stack ~8 deep on them. v6 (direct-L2 gather, no LDS) = 91us — all 128 groups
// co-resident -> 8MB/XCD working set vs 4MB L2 -> 307MB HBM over-fetch. v7 keeps v5's proven
// staging/control flow but stores S[k][node] (stride 260): the gather instruction has uniform k
// across lanes, so bank = (4k + node) mod 32 with node random -> uniform over ALL 32 banks
// (λ=2/bank ≈ the free 2-way regime). Transpose happens on the staging write (float4 global
// load -> 4x ds_write_b32, which lands exactly 2-way = free). Accumulation order (k=0..15 per
// t, t ascending) is bitwise-identical to v5's passing code. ----------------
__global__ __launch_bounds__(256, 4) void score_v7(const float* __restrict__ pq, const int* __restrict__ ei,
                                                   const float* __restrict__ wm2, const float* __restrict__ bm2,
                                                   float* __restrict__ out) {
  __shared__ float S[2 * 16 * 260];   // 33.3 KB -> 4 blocks/CU (same occupancy as v5's 40KB)
  const int tid = threadIdx.x;
  const int g = blockIdx.x & 127;       // same-g blocks ≡ g (mod 8) -> same XCD, pq L2 reuse
  const int eighth = blockIdx.x >> 7;
  const int gbase = g * NPG_;
  const int ebase = g * EPG_ + eighth * 512;
  int rl[2], cl[2];
  float acc[2] = {};
#pragma unroll
  for (int j = 0; j < 2; ++j) {
    int e = ebase + j * 256 + tid;
    rl[j] = ei[e] - gbase;
    cl[j] = ei[EE_ + e] - gbase;
  }
  for (int t = 0; t < 16; ++t) {
    __syncthreads();
#pragma unroll
    for (int it = 0; it < 4; ++it) {
      int idx = tid + it * 256;           // 0..1023: 256 nodes x 4 k-quads
      int node = idx >> 2, k4 = (idx & 3) * 4;
      const float* src = &pq[(size_t)(gbase + node) * 512 + t * 16 + k4];
      float4 p = *(const float4*)src;
      float4 q = *(const float4*)(src + 256);
      // write-side transpose; banks = (16j + 4i + c + (lane>>2)) mod 32 -> exact 2-way = free
      S[(k4 + 0) * 260 + node] = p.x;
      S[(k4 + 1) * 260 + node] = p.y;
      S[(k4 + 2) * 260 + node] = p.z;
      S[(k4 + 3) * 260 + node] = p.w;
      S[4160 + (k4 + 0) * 260 + node] = q.x;
      S[4160 + (k4 + 1) * 260 + node] = q.y;
      S[4160 + (k4 + 2) * 260 + node] = q.z;
      S[4160 + (k4 + 3) * 260 + node] = q.w;
    }
    __syncthreads();
    float wv[16];
#pragma unroll
    for (int k = 0; k < 16; ++k) wv[k] = wm2[t * 16 + k];  // uniform -> SGPR
#pragma unroll
    for (int j = 0; j < 2; ++j) {
      const float* Pb = &S[rl[j]];
      const float* Qb = &S[4160 + cl[j]];
      float pv[16], qv[16];
#pragma unroll
      for (int k = 0; k < 16; ++k) {      // batch loads: 32 independent ds_read_b32 in flight
        pv[k] = Pb[k * 260];
        qv[k] = Qb[k * 260];
      }
      float a = acc[j];
#pragma unroll
      for (int k = 0; k < 16; ++k)        // same fp order as v5: k ascending within t
        a = fmaf(wv[k], fmaxf(pv[k] + qv[k], 0.f), a);
      acc[j] = a;
    }
  }
  const float beta = bm2[0];
#pragma unroll
  for (int j = 0; j < 2; ++j) out[ebase + j * 256 + tid] = acc[j] + beta;
}

// ---------------- bitonic argsort v4 (proven): registers + shfl_xor; LDS only for j>=256 ----------------
__global__ __launch_bounds__(1024) void sort_kernel(float* __restrict__ out, const int* __restrict__ ei,
                                                    int* __restrict__ kg, int* __restrict__ dg,
                                                    int* __restrict__ cmask, int* __restrict__ dmask) {
  __shared__ u64 keys[EPG_];
  const int g = blockIdx.x;
  const int tid = threadIdx.x;
  const int b = 4 * tid;
  u64 e[4];
  {
    float4 s4 = *(const float4*)&out[g * EPG_ + b];
    float sv[4] = {s4.x, s4.y, s4.z, s4.w};
#pragma unroll
    for (int s = 0; s < 4; ++s) {
      unsigned u = __float_as_uint(sv[s]);
      u = (u & 0x80000000u) ? ~u : (u | 0x80000000u);
      e[s] = ((u64)u << 32) | (unsigned)(~(b + s));
    }
  }
  cswap(e[0], e[1], true);
  cswap(e[2], e[3], false);
  {
    bool d = ((b & 4) == 0);
    cswap(e[0], e[2], d); cswap(e[1], e[3], d);
    cswap(e[0], e[1], d); cswap(e[2], e[3], d);
  }
  for (int k = 8; k <= EPG_; k <<= 1) {
    if (k >= 512) {
#pragma unroll
      for (int s = 0; s < 4; ++s) keys[b + s] = e[s];
      __syncthreads();
      for (int j = k >> 1; j >= 256; j >>= 1) {
        const int jm1 = j - 1;
        const int p0 = tid, p1 = tid + 1024;
        const int i0 = ((p0 & ~jm1) << 1) | (p0 & jm1);
        const int i1 = ((p1 & ~jm1) << 1) | (p1 & jm1);
        u64 a0 = keys[i0], b0 = keys[i0 + j];
        u64 a1 = keys[i1], b1 = keys[i1 + j];
        bool d0 = ((i0 & k) == 0), d1 = ((i1 & k) == 0);
        u64 hi0 = a0 > b0 ? a0 : b0, lo0 = a0 > b0 ? b0 : a0;
        u64 hi1 = a1 > b1 ? a1 : b1, lo1 = a1 > b1 ? b1 : a1;
        keys[i0]     = d0 ? hi0 : lo0;
        keys[i0 + j] = d0 ? lo0 : hi0;
        keys[i1]     = d1 ? hi1 : lo1;
        keys[i1 + j] = d1 ? lo1 : hi1;
        __syncthreads();
      }
#pragma unroll
      for (int s = 0; s < 4; ++s) e[s] = keys[b + s];
    }
    const bool d = ((tid & (k >> 2)) == 0);
    for (int j = (k >> 1) > 128 ? 128 : (k >> 1); j >= 4; j >>= 1) {
      const int delta = j >> 2;
      const bool lower = ((tid & delta) == 0);
      const bool keepmax = (lower == d);
#pragma unroll
      for (int s = 0; s < 4; ++s) {
        u64 p = __shfl_xor(e[s], delta);
        u64 mx = e[s] > p ? e[s] : p;
        u64 mn = e[s] > p ? p : e[s];
        e[s] = keepmax ? mx : mn;
      }
    }
    cswap(e[0], e[2], d); cswap(e[1], e[3], d);
    cswap(e[0], e[1], d); cswap(e[2], e[3], d);
  }
#pragma unroll
  for (int s = 0; s < 4; ++s) {
    const int p = b + s;
    u64 kv = e[s];
    int i = (int)(~(unsigned)kv);
    unsigned hi = (unsigned)(kv >> 32);
    unsigned ub = (hi & 0x80000000u) ? (hi ^ 0x80000000u) : ~hi;
    float sc = __uint_as_float(ub);
    int ed = g * EPG_ + i;
    int r = ei[ed], c = ei[EE_ + ed];
    if (p < KK_) {
      out[O_CW + g * KK_ + p] = sc;
      kg[g * KK_ + p] = ed;
      cmask[r] = 1; cmask[c] = 1;
    } else {
      int q = p - KK_;
      out[O_DW + g * KK_ + q] = -sc;
      dg[g * KK_ + q] = ed;
      dmask[r] = 1; dmask[c] = 1;
    }
  }
}

// ---------------- inclusive scan of masks -> nid (cumsum-1); 1 block per mask ----------------
__global__ __launch_bounds__(1024) void scan_kernel(const int* __restrict__ masks, int* __restrict__ nids) {
  const int which = blockIdx.x;
  const int* m = masks + which * NN_;
  int* nid = nids + which * NN_;
  const int tid = threadIdx.x;
  const int base = tid * 32;
  int local[32];
  int sum = 0;
#pragma unroll
  for (int j = 0; j < 32; ++j) { local[j] = m[base + j]; sum += local[j]; }
  __shared__ int ps[1024];
  ps[tid] = sum;
  __syncthreads();
  for (int off = 1; off < 1024; off <<= 1) {
    int v = (tid >= off) ? ps[tid - off] : 0;
    __syncthreads();
    ps[tid] += v;
    __syncthreads();
  }
  int run = ps[tid] - sum;
#pragma unroll
  for (int j = 0; j < 32; ++j) { run += local[j]; nid[base + j] = run - 1; }
}

// ---------------- final gathers ----------------
__global__ __launch_bounds__(256) void finalize_kernel(const int* __restrict__ kg, const int* __restrict__ dg,
                                                       const int* __restrict__ ei,
                                                       const int* __restrict__ nid_c, const int* __restrict__ nid_d,
                                                       const int* __restrict__ cmask, const int* __restrict__ dmask,
                                                       float* __restrict__ out) {
  const int p = blockIdx.x * 256 + threadIdx.x;
  int e = kg[p];
  out[O_CEI + p]       = (float)nid_c[ei[e]];
  out[O_CEI + GK_ + p] = (float)nid_c[ei[EE_ + e]];
  int e2 = dg[p];
  out[O_FEI + p]       = (float)nid_d[ei[e2]];
  out[O_FEI + GK_ + p] = (float)nid_d[ei[EE_ + e2]];
  if (p < NN_) {
    out[O_CM + p] = (float)cmask[p];
    out[O_DM + p] = (float)dmask[p];
  }
}

extern "C" void kernel_launch(void* const* d_in, const int* in_sizes, int n_in,
                              void* d_out, int out_size, void* d_ws, size_t ws_size,
                              hipStream_t stream) {
  (void)in_sizes; (void)n_in; (void)out_size; (void)ws_size;
  const float* x   = (const float*)d_in[0];
  const float* ea  = (const float*)d_in[1];
  const float* W11 = (const float*)d_in[2];
  const float* b11 = (const float*)d_in[3];
  const float* W12 = (const float*)d_in[4];
  const float* W13 = (const float*)d_in[5];
  const float* b13 = (const float*)d_in[6];
  const float* W21 = (const float*)d_in[7];
  const float* b21 = (const float*)d_in[8];
  const float* W22 = (const float*)d_in[9];
  const float* W23 = (const float*)d_in[10];
  const float* b23 = (const float*)d_in[11];
  const float* Wm1 = (const float*)d_in[12];
  const float* bm1 = (const float*)d_in[13];
  const float* Wm2 = (const float*)d_in[14];
  const float* bm2 = (const float*)d_in[15];
  const int*   ei  = (const int*)d_in[16];
  float* out = (float*)d_out;
  float* ws  = (float*)d_ws;

  // workspace (float offsets), phase-overlapped (unchanged 78.1 MB footprint):
  //   MT  [0, 8388608)          32 MB   (dead after mm_agg #2; fully written by build_dense — no memset)
  //   Wc  [8388608, 8421376)    128 KB  (fully written by build_dense)
  //   buf [8421376, 14712832)   24 MB   (dead after mm_agg #2)
  //   pq  [0, 16777216)         64 MB   overlaps MT/Wc/buf, written after all dead
  //   h_c [16777216, 18874368)  8 MB
  //   ints from 18874368: kg GK, dg GK, cmask N, dmask N, nid_c N, nid_d N
  //   WT aliases kg: WmT 32768 + W1T 12288 + W2T 12288 = 57344 floats < GK.
  float* MT  = ws;
  float* Wc  = ws + 8388608;
  float* buf = ws + 8421376;
  float* pq  = ws;
  float* h_c = ws + 16777216;
  int* kg    = (int*)(ws + 18874368);
  int* dg    = kg + GK_;
  int* cmask = dg + GK_;
  int* dmask = cmask + NN_;
  int* nid_c = dmask + NN_;
  int* nid_d = nid_c + NN_;
  float* WmT = ws + 18874368;            // aliases kg
  float* W1T = WmT + 32768;
  float* W2T = W1T + 12288;

  prep_kernel<<<160, 256, 0, stream>>>(Wm1, W11, W12, W13, W21, W22, W23, WmT, W1T, W2T, cmask);

  build_dense<<<256, 256, 0, stream>>>(ei, ea, MT, Wc);

  BiasCfg bc1{};
  bc1.b[0] = b11; bc1.b[1] = nullptr; bc1.b[2] = b13;
  gemm_wt<<<512, 256, 0, stream>>>(x, 64, W1T, 192, bc1, 3, buf, 192);

  mm_agg<<<512, 256, 0, stream>>>(MT, buf, Wc, h_c, /*relu=*/1);

  BiasCfg bc2{};
  bc2.b[0] = b21; bc2.b[1] = nullptr; bc2.b[2] = b23;
  gemm_wt<<<512, 256, 0, stream>>>(h_c, 64, W2T, 192, bc2, 3, buf, 192);

  mm_agg<<<512, 256, 0, stream>>>(MT, buf, Wc, h_c, /*relu=*/0);

  BiasCfg bc3{};
  for (int cb = 0; cb < 4; ++cb) { bc3.b[cb] = bm1 + cb * 64; bc3.b[cb + 4] = nullptr; }
  gemm_wt<<<512, 256, 0, stream>>>(h_c, 64, WmT, 512, bc3, 8, pq, 512);

  score_v7<<<1024, 256, 0, stream>>>(pq, ei, Wm2, bm2, out);

  sort_kernel<<<G_, 1024, 0, stream>>>(out, ei, kg, dg, cmask, dmask);

  scan_kernel<<<2, 1024, 0, stream>>>(cmask, nid_c);

  finalize_kernel<<<GK_ / 256, 256, 0, stream>>>(kg, dg, ei, nid_c, nid_d, cmask, dmask, out);
}

// Round 3
// 326.670 us; speedup vs baseline: 1.1292x; 1.0641x over previous
//
#include <hip/hip_runtime.h>
#include <cstddef>

#define G_    128
#define NPG_  256
#define EPG_  4096
#define NN_   32768
#define EE_   524288
#define KK_   2048
#define GK_   262144

// d_out layout (floats): [score E][causal_w GK][conf_w GK][causal_ei 2*GK][conf_ei 2*GK][cmask N][dmask N]
#define O_CW  524288
#define O_DW  786432
#define O_CEI 1048576
#define O_FEI 1572864
#define O_CM  2097152
#define O_DM  2129920

typedef float v4f __attribute__((ext_vector_type(4)));
typedef unsigned long long u64;

struct BiasCfg {
  const float* b[8];
};

__device__ __forceinline__ void cswap(u64& a, u64& b, bool d) {
  u64 hi = a > b ? a : b, lo = a > b ? b : a;
  a = d ? hi : lo;
  b = d ? lo : hi;
}

// ---------------- GEMM body, W from pre-transposed global; nt-envelope rule (r6/7/8/9/13):
// <=1 outstanding nt panel stream per block — enforce with __syncthreads() AFTER each cb's
// store burst. Removing that barrier (r13) caused ~20x HBM write amplification. ----------------
__device__ __forceinline__ void gemm_wt_body(const float* __restrict__ in, int istride,
                                             const float* __restrict__ WT, int wstride,
                                             const BiasCfg& bc, int ncb,
                                             float* __restrict__ out, int ostride,
                                             int bx, float* xT) {
  const int tid = threadIdx.x;
  const int r0 = bx * 64;
#pragma unroll
  for (int it = 0; it < 16; ++it) {
    int idx = tid + it * 256;
    int rr = idx >> 6, kk = idx & 63;
    xT[kk * 68 + rr] = in[(r0 + rr) * istride + kk];
  }
  __syncthreads();
  const int c4 = (tid & 15) * 4;
  const int r4 = (tid >> 4) * 4;
  for (int cb = 0; cb < ncb; ++cb) {
    const float* wp = WT + cb * 64 + c4;
    const float* bp = bc.b[cb];
    float acc[4][4] = {};
#pragma unroll
    for (int k = 0; k < 64; ++k) {
      float4 xv = *(const float4*)&xT[k * 68 + r4];
      float4 wv = *(const float4*)&wp[(size_t)k * wstride];
      float xr[4] = {xv.x, xv.y, xv.z, xv.w};
      float wc[4] = {wv.x, wv.y, wv.z, wv.w};
#pragma unroll
      for (int a = 0; a < 4; ++a)
#pragma unroll
        for (int b = 0; b < 4; ++b)
          acc[a][b] = fmaf(xr[a], wc[b], acc[a][b]);
    }
    float bx4[4] = {0.f, 0.f, 0.f, 0.f};
    if (bp) {
      float4 bb = *(const float4*)&bp[c4];
      bx4[0] = bb.x; bx4[1] = bb.y; bx4[2] = bb.z; bx4[3] = bb.w;
    }
#pragma unroll
    for (int ri = 0; ri < 4; ++ri) {
      v4f st;
      st.x = acc[ri][0] + bx4[0];
      st.y = acc[ri][1] + bx4[1];
      st.z = acc[ri][2] + bx4[2];
      st.w = acc[ri][3] + bx4[3];
      __builtin_nontemporal_store(st, (v4f*)&out[(r0 + r4 + ri) * ostride + cb * 64 + c4]);
    }
    __syncthreads();  // drain nt burst (vmcnt(0)) — the nt-envelope invariant
  }
}

__global__ __launch_bounds__(256, 4) void gemm_wt(const float* __restrict__ in, int istride,
                                                  const float* __restrict__ WT, int wstride,
                                                  BiasCfg bc, int ncb,
                                                  float* __restrict__ out, int ostride) {
  __shared__ float xT[64 * 68];
  gemm_wt_body(in, istride, WT, wstride, bc, ncb, out, ostride, blockIdx.x, xT);
}

// ---------------- prep: weight transposes (WmT/W1T/W2T) + zero masks ----------------
__global__ __launch_bounds__(256) void prep_kernel(const float* __restrict__ Wm1,
                                                   const float* __restrict__ W11, const float* __restrict__ W12,
                                                   const float* __restrict__ W13,
                                                   const float* __restrict__ W21, const float* __restrict__ W22,
                                                   const float* __restrict__ W23,
                                                   float* __restrict__ WmT, float* __restrict__ W1T,
                                                   float* __restrict__ W2T, int* __restrict__ masks) {
  const int b = blockIdx.x;
  const int tid = threadIdx.x;
  if (b < 64) {
    const int k = b;
#pragma unroll
    for (int t = 0; t < 2; ++t) {
      int j = t * 256 + tid;
      int row = j & 255;
      int koff = (j < 256) ? 0 : 64;
      WmT[k * 512 + j] = Wm1[row * 128 + koff + k];
    }
  } else if (b < 80) {
    const int kb = (b - 64) * 4;
    if (tid < 192) {
      int cb = tid >> 6, c = tid & 63;
      const float* Wsrc = (cb == 0) ? W11 : (cb == 1) ? W12 : W13;
#pragma unroll
      for (int s = 0; s < 4; ++s) {
        int k = kb + s;
        W1T[k * 192 + tid] = Wsrc[c * 64 + k];
      }
    }
  } else if (b < 96) {
    const int kb = (b - 80) * 4;
    if (tid < 192) {
      int cb = tid >> 6, c = tid & 63;
      const float* Wsrc = (cb == 0) ? W21 : (cb == 1) ? W22 : W23;
#pragma unroll
      for (int s = 0; s < 4; ++s) {
        int k = kb + s;
        W2T[k * 192 + tid] = Wsrc[c * 64 + k];
      }
    }
  } else {
    int idx = (b - 96) * 1024 + tid * 4;  // 64 blocks x 1024 ints = 65536 = 2*NN
    int4 z = {0, 0, 0, 0};
    *(int4*)&masks[idx] = z;
  }
}

// ---------------- build_dense: per-(group, col-half) LDS accumulation — no global atomics,
// no MT memset (every cell written), Wc = LDS column sums (no contention) ----------------
__global__ __launch_bounds__(256) void build_dense(const int* __restrict__ ei, const float* __restrict__ ea,
                                                   float* __restrict__ MT, float* __restrict__ Wc) {
  __shared__ float acc[NPG_ * 128];  // 128 KB: 256 rows x 128 cols (this block's column half)
  const int tid = threadIdx.x;
  const int g = blockIdx.x >> 1;
  const int c0 = (blockIdx.x & 1) * 128;
  const int gbase = g * NPG_;
  const size_t mbase = (size_t)g << 16;
  for (int i = tid * 4; i < NPG_ * 128; i += 1024) {
    float4 z = {0.f, 0.f, 0.f, 0.f};
    *(float4*)&acc[i] = z;
  }
  __syncthreads();
  const int ebase = g * EPG_;
#pragma unroll
  for (int it = 0; it < 16; ++it) {
    int e = ebase + it * 256 + tid;
    int r = ei[e] - gbase;
    int ch = ei[EE_ + e] - gbase - c0;
    float w = ea[e];
    if ((unsigned)ch < 128u) atomicAdd(&acc[r * 128 + ch], w);
  }
  __syncthreads();
  // write the half-slab: each row contributes 512 B aligned chunk
  for (int i = tid; i < NPG_ * 32; i += 256) {
    int r = i >> 5, c4 = (i & 31) * 4;
    *(float4*)&MT[mbase + (size_t)r * 256 + c0 + c4] = *(const float4*)&acc[r * 128 + c4];
  }
  // Wc column sums (lanes own columns; per-lane serial over r)
  if (tid < 128) {
    float s = 0.f;
    for (int r = 0; r < NPG_; ++r) s += acc[r * 128 + tid];
    Wc[gbase + c0 + tid] = s;
  }
}

// ---------------- dense leconv aggregation: h[c] = sum_r MT[r][c]*A[r] - Wc[c]*B[c] + C[c]
// (v2: float4 staging — 4x fewer global-load and LDS-write instructions) ----------------
__global__ __launch_bounds__(256) void mm_agg(const float* __restrict__ MT, const float* __restrict__ buf,
                                              const float* __restrict__ Wc, float* __restrict__ hout,
                                              int do_relu) {
  __shared__ float Ms[64 * 72];
  __shared__ float As[64 * 72];
  const int tid = threadIdx.x;
  const int g = blockIdx.x >> 2;
  const int c0 = (blockIdx.x & 3) * 64;
  const int gbase = g * NPG_;
  const size_t mbase = (size_t)g << 16;
  const int c4 = (tid >> 4) * 4;   // output node within tile
  const int k4 = (tid & 15) * 4;   // feature (lane-contiguous)
  float acc[4][4] = {};
  for (int kc = 0; kc < 4; ++kc) {
#pragma unroll
    for (int it = 0; it < 4; ++it) {
      int idx = tid + it * 256;       // 0..1023
      int rr = idx >> 4, c16 = (idx & 15) * 4;
      *(float4*)&Ms[rr * 72 + c16] = *(const float4*)&MT[mbase + (size_t)(kc * 64 + rr) * 256 + c0 + c16];
      *(float4*)&As[rr * 72 + c16] = *(const float4*)&buf[(gbase + kc * 64 + rr) * 192 + c16];
    }
    __syncthreads();
#pragma unroll
    for (int r = 0; r < 64; ++r) {
      float4 mv = *(const float4*)&Ms[r * 72 + c4];
      float4 av = *(const float4*)&As[r * 72 + k4];
      float mr[4] = {mv.x, mv.y, mv.z, mv.w};
      float ak[4] = {av.x, av.y, av.z, av.w};
#pragma unroll
      for (int ci = 0; ci < 4; ++ci)
#pragma unroll
        for (int ki = 0; ki < 4; ++ki)
          acc[ci][ki] = fmaf(mr[ci], ak[ki], acc[ci][ki]);
    }
    __syncthreads();
  }
#pragma unroll
  for (int ci = 0; ci < 4; ++ci) {
    int n = gbase + c0 + c4 + ci;
    float wcn = Wc[n];
    float4 b4 = *(const float4*)&buf[n * 192 + 64 + k4];
    float4 cc4 = *(const float4*)&buf[n * 192 + 128 + k4];
    float4 st;
    st.x = acc[ci][0] - wcn * b4.x + cc4.x;
    st.y = acc[ci][1] - wcn * b4.y + cc4.y;
    st.z = acc[ci][2] - wcn * b4.z + cc4.z;
    st.w = acc[ci][3] - wcn * b4.w + cc4.w;
    if (do_relu) {
      st.x = fmaxf(st.x, 0.f); st.y = fmaxf(st.y, 0.f);
      st.z = fmaxf(st.z, 0.f); st.w = fmaxf(st.w, 0.f);
    }
    *(float4*)&hout[n * 64 + k4] = st;
  }
}

// ---------------- fused edge scores v8: v5 structure (node-major, b128 gathers) + EDGE DEALING.
// v5 = 54us, 1.2e7 conflict cycles: b128 start bank-quad class = (5r + k4/4) mod 8 — only 8
// classes, random rows stack ~8-deep with a bad tail. v7 (scalar feature-major) = 77us: random
// b32 costs 10.5 extra cyc/instr (Poisson max-stacking, NOT free 2-way) at 3x instr count.
// v8 insight: edges may be processed in ANY order (each writes its own out[e]). Counting-sort
// the block's 512 edges by key (r&7)<<3|(c&7) (LDS histogram + wave scan + scatter, once,
// amortized over 16 t-steps), then deal p = (lane>>3)*64 + (lane&7)*8 + batch — a bijection
// giving every gather instruction exactly 8 lanes per r-class (P gather at the conflict-free
// depth-8 b128 floor) and octile-sampled c-classes (Q mostly clean). Boundary misassignment
// ~8% (Poisson). Per-edge fp accumulation order unchanged -> scores bitwise-identical to v5.
// Sort records + histogram live in the 4-float row pads -> LDS stays exactly 40KB, 4 blocks/CU.
__global__ __launch_bounds__(256, 4) void score_v8(const float* __restrict__ pq, const int* __restrict__ ei,
                                                   const float* __restrict__ wm2, const float* __restrict__ bm2,
                                                   float* __restrict__ out) {
  __shared__ __align__(16) float S[10240];   // Ps=[0,5120) Qs=[5120,10240); rows stride 20: 16 data + 4 pad
  float* Ps = S;
  float* Qs = S + 5120;
  int* ip = (int*)S;
  const int tid = threadIdx.x;
  const int g = blockIdx.x & 127;       // same-g blocks ≡ g (mod 8) -> same XCD, pq L2 reuse
  const int eighth = blockIdx.x >> 7;
  const int gbase = g * NPG_;
  const int ebase = g * EPG_ + eighth * 512;
  // pad slot i (i in [0,1024)) -> float index (i>>2)*20 + 16 + (i&3); slots: sorted[0,512),
  // hist[512,576), off[576,640), cursor[640,704)
#define PADI(i) ((((i) >> 2) * 20) + 16 + ((i) & 3))
  if (tid < 192) ip[PADI(512 + tid)] = 0;
  int rr[2], cc[2], key[2];
#pragma unroll
  for (int j = 0; j < 2; ++j) {
    int e = ebase + j * 256 + tid;
    rr[j] = ei[e] - gbase;
    cc[j] = ei[EE_ + e] - gbase;
    key[j] = ((rr[j] & 7) << 3) | (cc[j] & 7);
  }
  __syncthreads();
#pragma unroll
  for (int j = 0; j < 2; ++j) atomicAdd(&ip[PADI(512 + key[j])], 1);
  __syncthreads();
  if (tid < 64) {                        // wave 0: exclusive scan of 64 bucket counts
    int v = ip[PADI(512 + tid)];
    int s = v;
#pragma unroll
    for (int d = 1; d < 64; d <<= 1) {
      int u = __shfl_up(s, d);
      if (tid >= d) s += u;
    }
    ip[PADI(576 + tid)] = s - v;
  }
  __syncthreads();
#pragma unroll
  for (int j = 0; j < 2; ++j) {
    int pos = ip[PADI(576 + key[j])] + atomicAdd(&ip[PADI(640 + key[j])], 1);
    ip[PADI(pos)] = (rr[j] << 17) | (cc[j] << 9) | (j * 256 + tid);
  }
  __syncthreads();
  int rl[2], cl[2], eo[2];
  {
    const int l = tid & 63, w = tid >> 6;
#pragma unroll
    for (int j = 0; j < 2; ++j) {
      int p = (l >> 3) * 64 + (l & 7) * 8 + (2 * w + j);   // bijective deal over [0,512)
      int rec = ip[PADI(p)];
      rl[j] = (rec >> 17) * 20;
      cl[j] = ((rec >> 9) & 255) * 20;
      eo[j] = ebase + (rec & 511);
    }
  }
  float acc[2] = {};
  for (int t = 0; t < 16; ++t) {
    __syncthreads();
#pragma unroll
    for (int it = 0; it < 4; ++it) {
      int idx = tid + it * 256;
      int node = idx >> 2, k4 = (idx & 3) * 4;
      const float* src = &pq[(size_t)(gbase + node) * 512 + t * 16 + k4];
      *(float4*)&Ps[node * 20 + k4] = *(const float4*)src;
      *(float4*)&Qs[node * 20 + k4] = *(const float4*)(src + 256);
    }
    __syncthreads();
#pragma unroll
    for (int k4 = 0; k4 < 16; k4 += 4) {
      float4 w4 = *(const float4*)&wm2[t * 16 + k4];
#pragma unroll
      for (int j = 0; j < 2; ++j) {
        float4 p = *(const float4*)&Ps[rl[j] + k4];
        float4 q = *(const float4*)&Qs[cl[j] + k4];
        acc[j] = fmaf(w4.x, fmaxf(p.x + q.x, 0.f), acc[j]);
        acc[j] = fmaf(w4.y, fmaxf(p.y + q.y, 0.f), acc[j]);
        acc[j] = fmaf(w4.z, fmaxf(p.z + q.z, 0.f), acc[j]);
        acc[j] = fmaf(w4.w, fmaxf(p.w + q.w, 0.f), acc[j]);
      }
    }
  }
  const float beta = bm2[0];
#pragma unroll
  for (int j = 0; j < 2; ++j) out[eo[j]] = acc[j] + beta;
#undef PADI
}

// ---------------- bitonic argsort v4 (proven): registers + shfl_xor; LDS only for j>=256 ----------------
__global__ __launch_bounds__(1024) void sort_kernel(float* __restrict__ out, const int* __restrict__ ei,
                                                    int* __restrict__ kg, int* __restrict__ dg,
                                                    int* __restrict__ cmask, int* __restrict__ dmask) {
  __shared__ u64 keys[EPG_];
  const int g = blockIdx.x;
  const int tid = threadIdx.x;
  const int b = 4 * tid;
  u64 e[4];
  {
    float4 s4 = *(const float4*)&out[g * EPG_ + b];
    float sv[4] = {s4.x, s4.y, s4.z, s4.w};
#pragma unroll
    for (int s = 0; s < 4; ++s) {
      unsigned u = __float_as_uint(sv[s]);
      u = (u & 0x80000000u) ? ~u : (u | 0x80000000u);
      e[s] = ((u64)u << 32) | (unsigned)(~(b + s));
    }
  }
  cswap(e[0], e[1], true);
  cswap(e[2], e[3], false);
  {
    bool d = ((b & 4) == 0);
    cswap(e[0], e[2], d); cswap(e[1], e[3], d);
    cswap(e[0], e[1], d); cswap(e[2], e[3], d);
  }
  for (int k = 8; k <= EPG_; k <<= 1) {
    if (k >= 512) {
#pragma unroll
      for (int s = 0; s < 4; ++s) keys[b + s] = e[s];
      __syncthreads();
      for (int j = k >> 1; j >= 256; j >>= 1) {
        const int jm1 = j - 1;
        const int p0 = tid, p1 = tid + 1024;
        const int i0 = ((p0 & ~jm1) << 1) | (p0 & jm1);
        const int i1 = ((p1 & ~jm1) << 1) | (p1 & jm1);
        u64 a0 = keys[i0], b0 = keys[i0 + j];
        u64 a1 = keys[i1], b1 = keys[i1 + j];
        bool d0 = ((i0 & k) == 0), d1 = ((i1 & k) == 0);
        u64 hi0 = a0 > b0 ? a0 : b0, lo0 = a0 > b0 ? b0 : a0;
        u64 hi1 = a1 > b1 ? a1 : b1, lo1 = a1 > b1 ? b1 : a1;
        keys[i0]     = d0 ? hi0 : lo0;
        keys[i0 + j] = d0 ? lo0 : hi0;
        keys[i1]     = d1 ? hi1 : lo1;
        keys[i1 + j] = d1 ? lo1 : hi1;
        __syncthreads();
      }
#pragma unroll
      for (int s = 0; s < 4; ++s) e[s] = keys[b + s];
    }
    const bool d = ((tid & (k >> 2)) == 0);
    for (int j = (k >> 1) > 128 ? 128 : (k >> 1); j >= 4; j >>= 1) {
      const int delta = j >> 2;
      const bool lower = ((tid & delta) == 0);
      const bool keepmax = (lower == d);
#pragma unroll
      for (int s = 0; s < 4; ++s) {
        u64 p = __shfl_xor(e[s], delta);
        u64 mx = e[s] > p ? e[s] : p;
        u64 mn = e[s] > p ? p : e[s];
        e[s] = keepmax ? mx : mn;
      }
    }
    cswap(e[0], e[2], d); cswap(e[1], e[3], d);
    cswap(e[0], e[1], d); cswap(e[2], e[3], d);
  }
#pragma unroll
  for (int s = 0; s < 4; ++s) {
    const int p = b + s;
    u64 kv = e[s];
    int i = (int)(~(unsigned)kv);
    unsigned hi = (unsigned)(kv >> 32);
    unsigned ub = (hi & 0x80000000u) ? (hi ^ 0x80000000u) : ~hi;
    float sc = __uint_as_float(ub);
    int ed = g * EPG_ + i;
    int r = ei[ed], c = ei[EE_ + ed];
    if (p < KK_) {
      out[O_CW + g * KK_ + p] = sc;
      kg[g * KK_ + p] = ed;
      cmask[r] = 1; cmask[c] = 1;
    } else {
      int q = p - KK_;
      out[O_DW + g * KK_ + q] = -sc;
      dg[g * KK_ + q] = ed;
      dmask[r] = 1; dmask[c] = 1;
    }
  }
}

// ---------------- inclusive scan of masks -> nid (cumsum-1); 1 block per mask ----------------
__global__ __launch_bounds__(1024) void scan_kernel(const int* __restrict__ masks, int* __restrict__ nids) {
  const int which = blockIdx.x;
  const int* m = masks + which * NN_;
  int* nid = nids + which * NN_;
  const int tid = threadIdx.x;
  const int base = tid * 32;
  int local[32];
  int sum = 0;
#pragma unroll
  for (int j = 0; j < 32; ++j) { local[j] = m[base + j]; sum += local[j]; }
  __shared__ int ps[1024];
  ps[tid] = sum;
  __syncthreads();
  for (int off = 1; off < 1024; off <<= 1) {
    int v = (tid >= off) ? ps[tid - off] : 0;
    __syncthreads();
    ps[tid] += v;
    __syncthreads();
  }
  int run = ps[tid] - sum;
#pragma unroll
  for (int j = 0; j < 32; ++j) { run += local[j]; nid[base + j] = run - 1; }
}

// ---------------- final gathers ----------------
__global__ __launch_bounds__(256) void finalize_kernel(const int* __restrict__ kg, const int* __restrict__ dg,
                                                       const int* __restrict__ ei,
                                                       const int* __restrict__ nid_c, const int* __restrict__ nid_d,
                                                       const int* __restrict__ cmask, const int* __restrict__ dmask,
                                                       float* __restrict__ out) {
  const int p = blockIdx.x * 256 + threadIdx.x;
  int e = kg[p];
  out[O_CEI + p]       = (float)nid_c[ei[e]];
  out[O_CEI + GK_ + p] = (float)nid_c[ei[EE_ + e]];
  int e2 = dg[p];
  out[O_FEI + p]       = (float)nid_d[ei[e2]];
  out[O_FEI + GK_ + p] = (float)nid_d[ei[EE_ + e2]];
  if (p < NN_) {
    out[O_CM + p] = (float)cmask[p];
    out[O_DM + p] = (float)dmask[p];
  }
}

extern "C" void kernel_launch(void* const* d_in, const int* in_sizes, int n_in,
                              void* d_out, int out_size, void* d_ws, size_t ws_size,
                              hipStream_t stream) {
  (void)in_sizes; (void)n_in; (void)out_size; (void)ws_size;
  const float* x   = (const float*)d_in[0];
  const float* ea  = (const float*)d_in[1];
  const float* W11 = (const float*)d_in[2];
  const float* b11 = (const float*)d_in[3];
  const float* W12 = (const float*)d_in[4];
  const float* W13 = (const float*)d_in[5];
  const float* b13 = (const float*)d_in[6];
  const float* W21 = (const float*)d_in[7];
  const float* b21 = (const float*)d_in[8];
  const float* W22 = (const float*)d_in[9];
  const float* W23 = (const float*)d_in[10];
  const float* b23 = (const float*)d_in[11];
  const float* Wm1 = (const float*)d_in[12];
  const float* bm1 = (const float*)d_in[13];
  const float* Wm2 = (const float*)d_in[14];
  const float* bm2 = (const float*)d_in[15];
  const int*   ei  = (const int*)d_in[16];
  float* out = (float*)d_out;
  float* ws  = (float*)d_ws;

  // workspace (float offsets), phase-overlapped (unchanged 78.1 MB footprint):
  //   MT  [0, 8388608)          32 MB   (dead after mm_agg #2; fully written by build_dense — no memset)
  //   Wc  [8388608, 8421376)    128 KB  (fully written by build_dense)
  //   buf [8421376, 14712832)   24 MB   (dead after mm_agg #2)
  //   pq  [0, 16777216)         64 MB   overlaps MT/Wc/buf, written after all dead
  //   h_c [16777216, 18874368)  8 MB
  //   ints from 18874368: kg GK, dg GK, cmask N, dmask N, nid_c N, nid_d N
  //   WT aliases kg: WmT 32768 + W1T 12288 + W2T 12288 = 57344 floats < GK.
  float* MT  = ws;
  float* Wc  = ws + 8388608;
  float* buf = ws + 8421376;
  float* pq  = ws;
  float* h_c = ws + 16777216;
  int* kg    = (int*)(ws + 18874368);
  int* dg    = kg + GK_;
  int* cmask = dg + GK_;
  int* dmask = cmask + NN_;
  int* nid_c = dmask + NN_;
  int* nid_d = nid_c + NN_;
  float* WmT = ws + 18874368;            // aliases kg
  float* W1T = WmT + 32768;
  float* W2T = W1T + 12288;

  prep_kernel<<<160, 256, 0, stream>>>(Wm1, W11, W12, W13, W21, W22, W23, WmT, W1T, W2T, cmask);

  build_dense<<<256, 256, 0, stream>>>(ei, ea, MT, Wc);

  BiasCfg bc1{};
  bc1.b[0] = b11; bc1.b[1] = nullptr; bc1.b[2] = b13;
  gemm_wt<<<512, 256, 0, stream>>>(x, 64, W1T, 192, bc1, 3, buf, 192);

  mm_agg<<<512, 256, 0, stream>>>(MT, buf, Wc, h_c, /*relu=*/1);

  BiasCfg bc2{};
  bc2.b[0] = b21; bc2.b[1] = nullptr; bc2.b[2] = b23;
  gemm_wt<<<512, 256, 0, stream>>>(h_c, 64, W2T, 192, bc2, 3, buf, 192);

  mm_agg<<<512, 256, 0, stream>>>(MT, buf, Wc, h_c, /*relu=*/0);

  BiasCfg bc3{};
  for (int cb = 0; cb < 4; ++cb) { bc3.b[cb] = bm1 + cb * 64; bc3.b[cb + 4] = nullptr; }
  gemm_wt<<<512, 256, 0, stream>>>(h_c, 64, WmT, 512, bc3, 8, pq, 512);

  score_v8<<<1024, 256, 0, stream>>>(pq, ei, Wm2, bm2, out);

  sort_kernel<<<G_, 1024, 0, stream>>>(out, ei, kg, dg, cmask, dmask);

  scan_kernel<<<2, 1024, 0, stream>>>(cmask, nid_c);

  finalize_kernel<<<GK_ / 256, 256, 0, stream>>>(kg, dg, ei, nid_c, nid_d, cmask, dmask, out);
}

// Round 4
// 326.062 us; speedup vs baseline: 1.1313x; 1.0019x over previous
//
#include <hip/hip_runtime.h>
#include <cstddef>

#define G_    128
#define NPG_  256
#define EPG_  4096
#define NN_   32768
#define EE_   524288
#define KK_   2048
#define GK_   262144

// d_out layout (floats): [score E][causal_w GK][conf_w GK][causal_ei 2*GK][conf_ei 2*GK][cmask N][dmask N]
#define O_CW  524288
#define O_DW  786432
#define O_CEI 1048576
#define O_FEI 1572864
#define O_CM  2097152
#define O_DM  2129920

typedef float v4f __attribute__((ext_vector_type(4)));
typedef unsigned long long u64;

struct BiasCfg {
  const float* b[8];
};

__device__ __forceinline__ void cswap(u64& a, u64& b, bool d) {
  u64 hi = a > b ? a : b, lo = a > b ? b : a;
  a = d ? hi : lo;
  b = d ? lo : hi;
}

// ---------------- GEMM body, W from pre-transposed global; nt-envelope rule (r6/7/8/9/13):
// <=1 outstanding nt panel stream per block — enforce with __syncthreads() AFTER each cb's
// store burst. Removing that barrier (r13) caused ~20x HBM write amplification. ----------------
__device__ __forceinline__ void gemm_wt_body(const float* __restrict__ in, int istride,
                                             const float* __restrict__ WT, int wstride,
                                             const BiasCfg& bc, int ncb,
                                             float* __restrict__ out, int ostride,
                                             int bx, float* xT) {
  const int tid = threadIdx.x;
  const int r0 = bx * 64;
#pragma unroll
  for (int it = 0; it < 16; ++it) {
    int idx = tid + it * 256;
    int rr = idx >> 6, kk = idx & 63;
    xT[kk * 68 + rr] = in[(r0 + rr) * istride + kk];
  }
  __syncthreads();
  const int c4 = (tid & 15) * 4;
  const int r4 = (tid >> 4) * 4;
  for (int cb = 0; cb < ncb; ++cb) {
    const float* wp = WT + cb * 64 + c4;
    const float* bp = bc.b[cb];
    float acc[4][4] = {};
#pragma unroll
    for (int k = 0; k < 64; ++k) {
      float4 xv = *(const float4*)&xT[k * 68 + r4];
      float4 wv = *(const float4*)&wp[(size_t)k * wstride];
      float xr[4] = {xv.x, xv.y, xv.z, xv.w};
      float wc[4] = {wv.x, wv.y, wv.z, wv.w};
#pragma unroll
      for (int a = 0; a < 4; ++a)
#pragma unroll
        for (int b = 0; b < 4; ++b)
          acc[a][b] = fmaf(xr[a], wc[b], acc[a][b]);
    }
    float bx4[4] = {0.f, 0.f, 0.f, 0.f};
    if (bp) {
      float4 bb = *(const float4*)&bp[c4];
      bx4[0] = bb.x; bx4[1] = bb.y; bx4[2] = bb.z; bx4[3] = bb.w;
    }
#pragma unroll
    for (int ri = 0; ri < 4; ++ri) {
      v4f st;
      st.x = acc[ri][0] + bx4[0];
      st.y = acc[ri][1] + bx4[1];
      st.z = acc[ri][2] + bx4[2];
      st.w = acc[ri][3] + bx4[3];
      __builtin_nontemporal_store(st, (v4f*)&out[(r0 + r4 + ri) * ostride + cb * 64 + c4]);
    }
    __syncthreads();  // drain nt burst (vmcnt(0)) — the nt-envelope invariant
  }
}

__global__ __launch_bounds__(256, 4) void gemm_wt(const float* __restrict__ in, int istride,
                                                  const float* __restrict__ WT, int wstride,
                                                  BiasCfg bc, int ncb,
                                                  float* __restrict__ out, int ostride) {
  __shared__ float xT[64 * 68];
  gemm_wt_body(in, istride, WT, wstride, bc, ncb, out, ostride, blockIdx.x, xT);
}

// ---------------- prep: weight transposes (WmT/W1T/W2T) + zero masks ----------------
__global__ __launch_bounds__(256) void prep_kernel(const float* __restrict__ Wm1,
                                                   const float* __restrict__ W11, const float* __restrict__ W12,
                                                   const float* __restrict__ W13,
                                                   const float* __restrict__ W21, const float* __restrict__ W22,
                                                   const float* __restrict__ W23,
                                                   float* __restrict__ WmT, float* __restrict__ W1T,
                                                   float* __restrict__ W2T, int* __restrict__ masks) {
  const int b = blockIdx.x;
  const int tid = threadIdx.x;
  if (b < 64) {
    const int k = b;
#pragma unroll
    for (int t = 0; t < 2; ++t) {
      int j = t * 256 + tid;
      int row = j & 255;
      int koff = (j < 256) ? 0 : 64;
      WmT[k * 512 + j] = Wm1[row * 128 + koff + k];
    }
  } else if (b < 80) {
    const int kb = (b - 64) * 4;
    if (tid < 192) {
      int cb = tid >> 6, c = tid & 63;
      const float* Wsrc = (cb == 0) ? W11 : (cb == 1) ? W12 : W13;
#pragma unroll
      for (int s = 0; s < 4; ++s) {
        int k = kb + s;
        W1T[k * 192 + tid] = Wsrc[c * 64 + k];
      }
    }
  } else if (b < 96) {
    const int kb = (b - 80) * 4;
    if (tid < 192) {
      int cb = tid >> 6, c = tid & 63;
      const float* Wsrc = (cb == 0) ? W21 : (cb == 1) ? W22 : W23;
#pragma unroll
      for (int s = 0; s < 4; ++s) {
        int k = kb + s;
        W2T[k * 192 + tid] = Wsrc[c * 64 + k];
      }
    }
  } else {
    int idx = (b - 96) * 1024 + tid * 4;  // 64 blocks x 1024 ints = 65536 = 2*NN
    int4 z = {0, 0, 0, 0};
    *(int4*)&masks[idx] = z;
  }
}

// ---------------- build_dense: per-(group, col-half) LDS accumulation — no global atomics,
// no MT memset (every cell written), Wc = LDS column sums (no contention) ----------------
__global__ __launch_bounds__(256) void build_dense(const int* __restrict__ ei, const float* __restrict__ ea,
                                                   float* __restrict__ MT, float* __restrict__ Wc) {
  __shared__ float acc[NPG_ * 128];  // 128 KB: 256 rows x 128 cols (this block's column half)
  const int tid = threadIdx.x;
  const int g = blockIdx.x >> 1;
  const int c0 = (blockIdx.x & 1) * 128;
  const int gbase = g * NPG_;
  const size_t mbase = (size_t)g << 16;
  for (int i = tid * 4; i < NPG_ * 128; i += 1024) {
    float4 z = {0.f, 0.f, 0.f, 0.f};
    *(float4*)&acc[i] = z;
  }
  __syncthreads();
  const int ebase = g * EPG_;
#pragma unroll
  for (int it = 0; it < 16; ++it) {
    int e = ebase + it * 256 + tid;
    int r = ei[e] - gbase;
    int ch = ei[EE_ + e] - gbase - c0;
    float w = ea[e];
    if ((unsigned)ch < 128u) atomicAdd(&acc[r * 128 + ch], w);
  }
  __syncthreads();
  // write the half-slab: each row contributes 512 B aligned chunk
  for (int i = tid; i < NPG_ * 32; i += 256) {
    int r = i >> 5, c4 = (i & 31) * 4;
    *(float4*)&MT[mbase + (size_t)r * 256 + c0 + c4] = *(const float4*)&acc[r * 128 + c4];
  }
  // Wc column sums (lanes own columns; per-lane serial over r)
  if (tid < 128) {
    float s = 0.f;
    for (int r = 0; r < NPG_; ++r) s += acc[r * 128 + tid];
    Wc[gbase + c0 + tid] = s;
  }
}

// ---------------- dense leconv aggregation: h[c] = sum_r MT[r][c]*A[r] - Wc[c]*B[c] + C[c]
// (v2: float4 staging — 4x fewer global-load and LDS-write instructions) ----------------
__global__ __launch_bounds__(256) void mm_agg(const float* __restrict__ MT, const float* __restrict__ buf,
                                              const float* __restrict__ Wc, float* __restrict__ hout,
                                              int do_relu) {
  __shared__ float Ms[64 * 72];
  __shared__ float As[64 * 72];
  const int tid = threadIdx.x;
  const int g = blockIdx.x >> 2;
  const int c0 = (blockIdx.x & 3) * 64;
  const int gbase = g * NPG_;
  const size_t mbase = (size_t)g << 16;
  const int c4 = (tid >> 4) * 4;   // output node within tile
  const int k4 = (tid & 15) * 4;   // feature (lane-contiguous)
  float acc[4][4] = {};
  for (int kc = 0; kc < 4; ++kc) {
#pragma unroll
    for (int it = 0; it < 4; ++it) {
      int idx = tid + it * 256;       // 0..1023
      int rr = idx >> 4, c16 = (idx & 15) * 4;
      *(float4*)&Ms[rr * 72 + c16] = *(const float4*)&MT[mbase + (size_t)(kc * 64 + rr) * 256 + c0 + c16];
      *(float4*)&As[rr * 72 + c16] = *(const float4*)&buf[(gbase + kc * 64 + rr) * 192 + c16];
    }
    __syncthreads();
#pragma unroll
    for (int r = 0; r < 64; ++r) {
      float4 mv = *(const float4*)&Ms[r * 72 + c4];
      float4 av = *(const float4*)&As[r * 72 + k4];
      float mr[4] = {mv.x, mv.y, mv.z, mv.w};
      float ak[4] = {av.x, av.y, av.z, av.w};
#pragma unroll
      for (int ci = 0; ci < 4; ++ci)
#pragma unroll
        for (int ki = 0; ki < 4; ++ki)
          acc[ci][ki] = fmaf(mr[ci], ak[ki], acc[ci][ki]);
    }
    __syncthreads();
  }
#pragma unroll
  for (int ci = 0; ci < 4; ++ci) {
    int n = gbase + c0 + c4 + ci;
    float wcn = Wc[n];
    float4 b4 = *(const float4*)&buf[n * 192 + 64 + k4];
    float4 cc4 = *(const float4*)&buf[n * 192 + 128 + k4];
    float4 st;
    st.x = acc[ci][0] - wcn * b4.x + cc4.x;
    st.y = acc[ci][1] - wcn * b4.y + cc4.y;
    st.z = acc[ci][2] - wcn * b4.z + cc4.z;
    st.w = acc[ci][3] - wcn * b4.w + cc4.w;
    if (do_relu) {
      st.x = fmaxf(st.x, 0.f); st.y = fmaxf(st.y, 0.f);
      st.z = fmaxf(st.z, 0.f); st.w = fmaxf(st.w, 0.f);
    }
    *(float4*)&hout[n * 64 + k4] = st;
  }
}

// ---------------- fused edge scores v9: v8 counting-sort + PHASE-BALANCED dealing.
// v8's 64-lane-balanced deal was a null (conflicts 1.23e7 -> 1.27e7): evidence that LDS
// services a wave64 b128 in sub-wave phase groups (~16 lanes), and v8 made phase groups
// maximally imbalanced (lanes 0-15 -> r-classes {0,1} only, 8-deep). v9 construction:
// lane l targets r8=l&7, d=((l>>4)+4*((l>>3)&1))&7, c8=(r8+d)&7, key=r8*8+c8, rank=key*8+t
// (t=2w+j). Exact properties: bijective over 512 ranks; EVERY aligned 8-lane group covers
// all 8 r-classes once AND all 8 c-classes once -> balanced at 8/16/32/64-lane granularity,
// robust to the true phase width. P lands at the depth-2/phase floor; Q too, modulo
// counting-sort boundary smear (Poisson(8) buckets: r8 misassign ~12%, c8 ~50%, both +-1
// class only). Per-edge fp order unchanged -> scores bitwise-identical to v5/v8. ----------------
__global__ __launch_bounds__(256, 4) void score_v9(const float* __restrict__ pq, const int* __restrict__ ei,
                                                   const float* __restrict__ wm2, const float* __restrict__ bm2,
                                                   float* __restrict__ out) {
  __shared__ __align__(16) float S[10240];   // Ps=[0,5120) Qs=[5120,10240); rows stride 20: 16 data + 4 pad
  float* Ps = S;
  float* Qs = S + 5120;
  int* ip = (int*)S;
  const int tid = threadIdx.x;
  const int g = blockIdx.x & 127;       // same-g blocks ≡ g (mod 8) -> same XCD, pq L2 reuse
  const int eighth = blockIdx.x >> 7;
  const int gbase = g * NPG_;
  const int ebase = g * EPG_ + eighth * 512;
  // pad slot i (i in [0,1024)) -> float index (i>>2)*20 + 16 + (i&3); slots: sorted[0,512),
  // hist[512,576), off[576,640), cursor[640,704)
#define PADI(i) ((((i) >> 2) * 20) + 16 + ((i) & 3))
  if (tid < 192) ip[PADI(512 + tid)] = 0;
  int rr[2], cc[2], key[2];
#pragma unroll
  for (int j = 0; j < 2; ++j) {
    int e = ebase + j * 256 + tid;
    rr[j] = ei[e] - gbase;
    cc[j] = ei[EE_ + e] - gbase;
    key[j] = ((rr[j] & 7) << 3) | (cc[j] & 7);
  }
  __syncthreads();
#pragma unroll
  for (int j = 0; j < 2; ++j) atomicAdd(&ip[PADI(512 + key[j])], 1);
  __syncthreads();
  if (tid < 64) {                        // wave 0: exclusive scan of 64 bucket counts
    int v = ip[PADI(512 + tid)];
    int s = v;
#pragma unroll
    for (int d = 1; d < 64; d <<= 1) {
      int u = __shfl_up(s, d);
      if (tid >= d) s += u;
    }
    ip[PADI(576 + tid)] = s - v;
  }
  __syncthreads();
#pragma unroll
  for (int j = 0; j < 2; ++j) {
    int pos = ip[PADI(576 + key[j])] + atomicAdd(&ip[PADI(640 + key[j])], 1);
    ip[PADI(pos)] = (rr[j] << 17) | (cc[j] << 9) | (j * 256 + tid);
  }
  __syncthreads();
  int rl[2], cl[2], eo[2];
  {
    const int l = tid & 63, w = tid >> 6;
    const int r8 = l & 7;
    const int d8 = ((l >> 4) + ((l >> 3) & 1) * 4) & 7;   // distinct per 8-lane group
    const int c8 = (r8 + d8) & 7;
    const int tkey = r8 * 8 + c8;                         // lane -> key bijection per (w,j)
#pragma unroll
    for (int j = 0; j < 2; ++j) {
      int p = tkey * 8 + 2 * w + j;                       // bijective over [0,512)
      int rec = ip[PADI(p)];
      rl[j] = (rec >> 17) * 20;
      cl[j] = ((rec >> 9) & 255) * 20;
      eo[j] = ebase + (rec & 511);
    }
  }
  float acc[2] = {};
  for (int t = 0; t < 16; ++t) {
    __syncthreads();
#pragma unroll
    for (int it = 0; it < 4; ++it) {
      int idx = tid + it * 256;
      int node = idx >> 2, k4 = (idx & 3) * 4;
      const float* src = &pq[(size_t)(gbase + node) * 512 + t * 16 + k4];
      *(float4*)&Ps[node * 20 + k4] = *(const float4*)src;
      *(float4*)&Qs[node * 20 + k4] = *(const float4*)(src + 256);
    }
    __syncthreads();
#pragma unroll
    for (int k4 = 0; k4 < 16; k4 += 4) {
      float4 w4 = *(const float4*)&wm2[t * 16 + k4];
#pragma unroll
      for (int j = 0; j < 2; ++j) {
        float4 p = *(const float4*)&Ps[rl[j] + k4];
        float4 q = *(const float4*)&Qs[cl[j] + k4];
        acc[j] = fmaf(w4.x, fmaxf(p.x + q.x, 0.f), acc[j]);
        acc[j] = fmaf(w4.y, fmaxf(p.y + q.y, 0.f), acc[j]);
        acc[j] = fmaf(w4.z, fmaxf(p.z + q.z, 0.f), acc[j]);
        acc[j] = fmaf(w4.w, fmaxf(p.w + q.w, 0.f), acc[j]);
      }
    }
  }
  const float beta = bm2[0];
#pragma unroll
  for (int j = 0; j < 2; ++j) out[eo[j]] = acc[j] + beta;
#undef PADI
}

// ---------------- bitonic argsort v4 (proven): registers + shfl_xor; LDS only for j>=256 ----------------
__global__ __launch_bounds__(1024) void sort_kernel(float* __restrict__ out, const int* __restrict__ ei,
                                                    int* __restrict__ kg, int* __restrict__ dg,
                                                    int* __restrict__ cmask, int* __restrict__ dmask) {
  __shared__ u64 keys[EPG_];
  const int g = blockIdx.x;
  const int tid = threadIdx.x;
  const int b = 4 * tid;
  u64 e[4];
  {
    float4 s4 = *(const float4*)&out[g * EPG_ + b];
    float sv[4] = {s4.x, s4.y, s4.z, s4.w};
#pragma unroll
    for (int s = 0; s < 4; ++s) {
      unsigned u = __float_as_uint(sv[s]);
      u = (u & 0x80000000u) ? ~u : (u | 0x80000000u);
      e[s] = ((u64)u << 32) | (unsigned)(~(b + s));
    }
  }
  cswap(e[0], e[1], true);
  cswap(e[2], e[3], false);
  {
    bool d = ((b & 4) == 0);
    cswap(e[0], e[2], d); cswap(e[1], e[3], d);
    cswap(e[0], e[1], d); cswap(e[2], e[3], d);
  }
  for (int k = 8; k <= EPG_; k <<= 1) {
    if (k >= 512) {
#pragma unroll
      for (int s = 0; s < 4; ++s) keys[b + s] = e[s];
      __syncthreads();
      for (int j = k >> 1; j >= 256; j >>= 1) {
        const int jm1 = j - 1;
        const int p0 = tid, p1 = tid + 1024;
        const int i0 = ((p0 & ~jm1) << 1) | (p0 & jm1);
        const int i1 = ((p1 & ~jm1) << 1) | (p1 & jm1);
        u64 a0 = keys[i0], b0 = keys[i0 + j];
        u64 a1 = keys[i1], b1 = keys[i1 + j];
        bool d0 = ((i0 & k) == 0), d1 = ((i1 & k) == 0);
        u64 hi0 = a0 > b0 ? a0 : b0, lo0 = a0 > b0 ? b0 : a0;
        u64 hi1 = a1 > b1 ? a1 : b1, lo1 = a1 > b1 ? b1 : a1;
        keys[i0]     = d0 ? hi0 : lo0;
        keys[i0 + j] = d0 ? lo0 : hi0;
        keys[i1]     = d1 ? hi1 : lo1;
        keys[i1 + j] = d1 ? lo1 : hi1;
        __syncthreads();
      }
#pragma unroll
      for (int s = 0; s < 4; ++s) e[s] = keys[b + s];
    }
    const bool d = ((tid & (k >> 2)) == 0);
    for (int j = (k >> 1) > 128 ? 128 : (k >> 1); j >= 4; j >>= 1) {
      const int delta = j >> 2;
      const bool lower = ((tid & delta) == 0);
      const bool keepmax = (lower == d);
#pragma unroll
      for (int s = 0; s < 4; ++s) {
        u64 p = __shfl_xor(e[s], delta);
        u64 mx = e[s] > p ? e[s] : p;
        u64 mn = e[s] > p ? p : e[s];
        e[s] = keepmax ? mx : mn;
      }
    }
    cswap(e[0], e[2], d); cswap(e[1], e[3], d);
    cswap(e[0], e[1], d); cswap(e[2], e[3], d);
  }
#pragma unroll
  for (int s = 0; s < 4; ++s) {
    const int p = b + s;
    u64 kv = e[s];
    int i = (int)(~(unsigned)kv);
    unsigned hi = (unsigned)(kv >> 32);
    unsigned ub = (hi & 0x80000000u) ? (hi ^ 0x80000000u) : ~hi;
    float sc = __uint_as_float(ub);
    int ed = g * EPG_ + i;
    int r = ei[ed], c = ei[EE_ + ed];
    if (p < KK_) {
      out[O_CW + g * KK_ + p] = sc;
      kg[g * KK_ + p] = ed;
      cmask[r] = 1; cmask[c] = 1;
    } else {
      int q = p - KK_;
      out[O_DW + g * KK_ + q] = -sc;
      dg[g * KK_ + q] = ed;
      dmask[r] = 1; dmask[c] = 1;
    }
  }
}

// ---------------- inclusive scan of masks -> nid (cumsum-1); 1 block per mask ----------------
__global__ __launch_bounds__(1024) void scan_kernel(const int* __restrict__ masks, int* __restrict__ nids) {
  const int which = blockIdx.x;
  const int* m = masks + which * NN_;
  int* nid = nids + which * NN_;
  const int tid = threadIdx.x;
  const int base = tid * 32;
  int local[32];
  int sum = 0;
#pragma unroll
  for (int j = 0; j < 32; ++j) { local[j] = m[base + j]; sum += local[j]; }
  __shared__ int ps[1024];
  ps[tid] = sum;
  __syncthreads();
  for (int off = 1; off < 1024; off <<= 1) {
    int v = (tid >= off) ? ps[tid - off] : 0;
    __syncthreads();
    ps[tid] += v;
    __syncthreads();
  }
  int run = ps[tid] - sum;
#pragma unroll
  for (int j = 0; j < 32; ++j) { run += local[j]; nid[base + j] = run - 1; }
}

// ---------------- final gathers ----------------
__global__ __launch_bounds__(256) void finalize_kernel(const int* __restrict__ kg, const int* __restrict__ dg,
                                                       const int* __restrict__ ei,
                                                       const int* __restrict__ nid_c, const int* __restrict__ nid_d,
                                                       const int* __restrict__ cmask, const int* __restrict__ dmask,
                                                       float* __restrict__ out) {
  const int p = blockIdx.x * 256 + threadIdx.x;
  int e = kg[p];
  out[O_CEI + p]       = (float)nid_c[ei[e]];
  out[O_CEI + GK_ + p] = (float)nid_c[ei[EE_ + e]];
  int e2 = dg[p];
  out[O_FEI + p]       = (float)nid_d[ei[e2]];
  out[O_FEI + GK_ + p] = (float)nid_d[ei[EE_ + e2]];
  if (p < NN_) {
    out[O_CM + p] = (float)cmask[p];
    out[O_DM + p] = (float)dmask[p];
  }
}

extern "C" void kernel_launch(void* const* d_in, const int* in_sizes, int n_in,
                              void* d_out, int out_size, void* d_ws, size_t ws_size,
                              hipStream_t stream) {
  (void)in_sizes; (void)n_in; (void)out_size; (void)ws_size;
  const float* x   = (const float*)d_in[0];
  const float* ea  = (const float*)d_in[1];
  const float* W11 = (const float*)d_in[2];
  const float* b11 = (const float*)d_in[3];
  const float* W12 = (const float*)d_in[4];
  const float* W13 = (const float*)d_in[5];
  const float* b13 = (const float*)d_in[6];
  const float* W21 = (const float*)d_in[7];
  const float* b21 = (const float*)d_in[8];
  const float* W22 = (const float*)d_in[9];
  const float* W23 = (const float*)d_in[10];
  const float* b23 = (const float*)d_in[11];
  const float* Wm1 = (const float*)d_in[12];
  const float* bm1 = (const float*)d_in[13];
  const float* Wm2 = (const float*)d_in[14];
  const float* bm2 = (const float*)d_in[15];
  const int*   ei  = (const int*)d_in[16];
  float* out = (float*)d_out;
  float* ws  = (float*)d_ws;

  // workspace (float offsets), phase-overlapped (unchanged 78.1 MB footprint):
  //   MT  [0, 8388608)          32 MB   (dead after mm_agg #2; fully written by build_dense — no memset)
  //   Wc  [8388608, 8421376)    128 KB  (fully written by build_dense)
  //   buf [8421376, 14712832)   24 MB   (dead after mm_agg #2)
  //   pq  [0, 16777216)         64 MB   overlaps MT/Wc/buf, written after all dead
  //   h_c [16777216, 18874368)  8 MB
  //   ints from 18874368: kg GK, dg GK, cmask N, dmask N, nid_c N, nid_d N
  //   WT aliases kg: WmT 32768 + W1T 12288 + W2T 12288 = 57344 floats < GK.
  float* MT  = ws;
  float* Wc  = ws + 8388608;
  float* buf = ws + 8421376;
  float* pq  = ws;
  float* h_c = ws + 16777216;
  int* kg    = (int*)(ws + 18874368);
  int* dg    = kg + GK_;
  int* cmask = dg + GK_;
  int* dmask = cmask + NN_;
  int* nid_c = dmask + NN_;
  int* nid_d = nid_c + NN_;
  float* WmT = ws + 18874368;            // aliases kg
  float* W1T = WmT + 32768;
  float* W2T = W1T + 12288;

  prep_kernel<<<160, 256, 0, stream>>>(Wm1, W11, W12, W13, W21, W22, W23, WmT, W1T, W2T, cmask);

  build_dense<<<256, 256, 0, stream>>>(ei, ea, MT, Wc);

  BiasCfg bc1{};
  bc1.b[0] = b11; bc1.b[1] = nullptr; bc1.b[2] = b13;
  gemm_wt<<<512, 256, 0, stream>>>(x, 64, W1T, 192, bc1, 3, buf, 192);

  mm_agg<<<512, 256, 0, stream>>>(MT, buf, Wc, h_c, /*relu=*/1);

  BiasCfg bc2{};
  bc2.b[0] = b21; bc2.b[1] = nullptr; bc2.b[2] = b23;
  gemm_wt<<<512, 256, 0, stream>>>(h_c, 64, W2T, 192, bc2, 3, buf, 192);

  mm_agg<<<512, 256, 0, stream>>>(MT, buf, Wc, h_c, /*relu=*/0);

  BiasCfg bc3{};
  for (int cb = 0; cb < 4; ++cb) { bc3.b[cb] = bm1 + cb * 64; bc3.b[cb + 4] = nullptr; }
  gemm_wt<<<512, 256, 0, stream>>>(h_c, 64, WmT, 512, bc3, 8, pq, 512);

  score_v9<<<1024, 256, 0, stream>>>(pq, ei, Wm2, bm2, out);

  sort_kernel<<<G_, 1024, 0, stream>>>(out, ei, kg, dg, cmask, dmask);

  scan_kernel<<<2, 1024, 0, stream>>>(cmask, nid_c);

  finalize_kernel<<<GK_ / 256, 256, 0, stream>>>(kg, dg, ei, nid_c, nid_d, cmask, dmask, out);
}